// Round 2
// baseline (10390.342 us; speedup 1.0000x reference)
//
#include <hip/hip_runtime.h>

typedef __bf16 bf16x8 __attribute__((ext_vector_type(8)));
typedef float  f32x4  __attribute__((ext_vector_type(4)));

#define Z0S 520   // z0 row (elems): [h_row 0:256 | h_col 256:512 | x 512:520]
#define Z1S 1032  // z1 row: [h_row | h_col | x_row 512:768 | x_col 768:1024] + 8 pad
#define W0_ELEMS (1536 * 520)
#define W1_ELEMS (1536 * 1024)
#define XB_ELEMS (2 * 64 * 32 * 512)   // [slot][b][m][c] bf16, c = region*256+col

__device__ __forceinline__ unsigned short f2bf(float f) {
    unsigned int u = __builtin_bit_cast(unsigned int, f);
    u += 0x7fffu + ((u >> 16) & 1u);   // RNE
    return (unsigned short)(u >> 16);
}
__device__ __forceinline__ float sigm(float x) {
    x = fminf(30.f, fmaxf(-30.f, x));
    return __fdividef(1.0f, 1.0f + __expf(-x));
}
__device__ __forceinline__ float ftanh(float x) {
    x = fminf(15.f, fmaxf(-15.f, x));
    float e = __expf(2.0f * x);
    return 1.0f - __fdividef(2.0f, e + 1.0f);
}
__device__ __forceinline__ bf16x8 zero8() {
    bf16x8 v;
#pragma unroll
    for (int i = 0; i < 8; ++i) v[i] = (__bf16)0.0f;
    return v;
}

// fp32 -> bf16 weight conversion + flag zeroing (ws re-poisoned each launch)
__global__ void convert_w(const float* __restrict__ W0f, const float* __restrict__ W1f,
                          unsigned short* __restrict__ Wb, int* __restrict__ flags) {
    const int gid = blockIdx.x * blockDim.x + threadIdx.x;
    if (gid < 256) flags[gid] = 0;
    const int total = W0_ELEMS + W1_ELEMS;
    for (int i = gid; i < total; i += gridDim.x * blockDim.x) {
        const float v = (i < W0_ELEMS) ? W0f[i] : W1f[i - W0_ELEMS];
        Wb[i] = f2bf(v);
    }
}

// 128 blocks = 64 batches x 2 column-slices. Slice s owns gate cols
// [s*128, s*128+128) of each 256-wide group -> each block streams only HALF
// the weights per step (2.37 MB), and the XCD mapping (slice = (bid&7)>>2)
// keeps one slice's weight set (2.26 MiB) L2-resident per XCD.
// 16 waves = 8 col-groups x 2 m-tiles; the m-pair loads identical weight
// addresses (L1 hit). fp32 recurrent state is block-local (block owns all 32
// rows of its cols). bf16 z-images cross blocks via parity-double-buffered
// global exchange + release/acquire agent-scope flags. 128 blocks at 1
// block/CU (115.7 KB LDS) on 256 CUs -> all co-resident; spins are capped so
// a scheduling surprise fails loud instead of hanging.
__global__ __launch_bounds__(1024, 4) void witran_coop(
    const float* __restrict__ inp,             // (64,32,32,8) fp32
    const unsigned short* __restrict__ W0,     // (1536,520)  bf16
    const unsigned short* __restrict__ W1,     // (1536,1024) bf16
    const float* __restrict__ Bias,            // (2,1536)    fp32
    float* __restrict__ out,                   // fp32 outputs
    unsigned short* __restrict__ xb0,          // exchange: layer-0 images
    unsigned short* __restrict__ xb1,          // exchange: layer-1 state
    int* __restrict__ flags)                   // [128] f0 | [128] f1
{
    const int bid  = blockIdx.x;
    const int s    = (bid & 7) >> 2;                 // slice 0/1
    const int b    = (bid >> 3) * 4 + (bid & 3);     // batch 0..63
    const int ps   = 1 - s;
    const int tid  = threadIdx.x;
    const int wave = tid >> 6;                       // 0..15
    const int cg   = wave >> 1;                      // col-group 0..7
    const int mh   = wave & 1;                       // m-tile 0/1
    const int lane = tid & 63;
    const int quad = lane >> 4;
    const int l16  = lane & 15;
    const int jl   = cg * 16 + l16;                  // local col 0..127
    const int jj   = s * 128 + jl;                   // absolute col 0..255
    const int pcol = ps * 128;

    int* f0 = flags;
    int* f1 = flags + 128;
    const int fown = b * 2 + s, fpar = b * 2 + ps;

    __shared__ __align__(16) unsigned short z0[32 * Z0S];
    __shared__ __align__(16) unsigned short z1[32 * Z1S];
    __shared__ float rollbuf[32 * 128];

    for (int idx = tid; idx < 32 * Z0S; idx += 1024) z0[idx] = 0;
    for (int idx = tid; idx < 32 * Z1S; idx += 1024) z1[idx] = 0;
    __syncthreads();
    if (tid < 256) {                           // stage x for t=0
        const int m = tid >> 3, i = tid & 7;
        const int c = 0 - m;
        float v = 0.f;
        if (c >= 0 && c < 32) v = inp[((b * 32 + m) * 32 + c) * 8 + i];
        z0[m * Z0S + 512 + i] = f2bf(v);
    }

    float biasr[2][6];
#pragma unroll
    for (int L = 0; L < 2; ++L)
#pragma unroll
        for (int G = 0; G < 6; ++G)
            biasr[L][G] = Bias[L * 1536 + G * 256 + jj];

    // fp32 state: [layer][p] <-> row m = mh*16+quad*4+p, col jj
    float hrreg[2][4], hcreg[2][4], hcn[4];
#pragma unroll
    for (int L = 0; L < 2; ++L)
#pragma unroll
        for (int p = 0; p < 4; ++p) { hrreg[L][p] = 0.f; hcreg[L][p] = 0.f; }

    const unsigned short* pW0[6];
    const unsigned short* pW1[6];
#pragma unroll
    for (int G = 0; G < 6; ++G) {
        pW0[G] = W0 + (size_t)(G * 256 + jj) * 520;
        pW1[G] = W1 + (size_t)(G * 256 + jj) * 1024;
    }
    const unsigned short* aB0 = &z0[(mh * 16 + l16) * Z0S];
    const unsigned short* aB1 = &z1[(mh * 16 + l16) * Z1S];

    __syncthreads();

    const size_t OUT1 = 66060288u;           // hidden_row_all (64,2,32,256)
    const size_t OUT2 = OUT1 + 1048576u;     // hidden_col_all (64,2,32,256)

    for (int t = 0; t < 63; ++t) {
        // ============ phase A: GEMM0 (reads z0) + gating0 ============
        f32x4 acc[6];
#pragma unroll
        for (int G = 0; G < 6; ++G) acc[G] = (f32x4){0.f, 0.f, 0.f, 0.f};

#pragma unroll
        for (int ks = 0; ks < 16; ++ks) {
            const int k0 = ks * 32 + quad * 8;
            bf16x8 a0 = *(const bf16x8*)&aB0[k0];
#pragma unroll
            for (int G = 0; G < 6; ++G) {
                bf16x8 bf = *(const bf16x8*)&pW0[G][k0];
                acc[G] = __builtin_amdgcn_mfma_f32_16x16x32_bf16(a0, bf, acc[G], 0, 0, 0);
            }
        }
        {   // partial k-step: x cols 512..519 on quad 0; quads 1-3 contribute zero
            const bf16x8 z8 = zero8();
            bf16x8 a0 = z8;
            if (quad == 0) a0 = *(const bf16x8*)&aB0[512];
#pragma unroll
            for (int G = 0; G < 6; ++G) {
                bf16x8 bf = z8;
                if (quad == 0) bf = *(const bf16x8*)&pW0[G][512];
                acc[G] = __builtin_amdgcn_mfma_f32_16x16x32_bf16(a0, bf, acc[G], 0, 0, 0);
            }
        }

#pragma unroll
        for (int p = 0; p < 4; ++p) {
            const int m = mh * 16 + quad * 4 + p;
            float g0 = acc[0][p], g1 = acc[1][p], g2 = acc[2][p];
            float g3 = acc[3][p], g4 = acc[4][p], g5 = acc[5][p];
            if ((t < 32) && (m <= t)) {
                g0 += biasr[0][0]; g1 += biasr[0][1]; g2 += biasr[0][2];
                g3 += biasr[0][3]; g4 += biasr[0][4]; g5 += biasr[0][5];
            }
            const float u_r = sigm(g0), o_r = sigm(g1), u_c = sigm(g2), o_c = sigm(g3);
            const float i_r = ftanh(g4), i_c = ftanh(g5);
            const float hrp = hrreg[0][p];
            const float hcp = hcreg[0][p];
            hrreg[0][p] = ftanh((1.f - u_r) * hrp + u_r * i_r) * o_r;
            hcn[p]      = ftanh((1.f - u_c) * hcp + u_c * i_c) * o_c;
        }
        __syncthreads();   // B1: all z0 reads of step t done

        // ============ phase B: layer-0 epilogue + publish ============
#pragma unroll
        for (int p = 0; p < 4; ++p) {
            const int m  = mh * 16 + quad * 4 + p;
            const float hrf = hrreg[0][p];
            const float hcf = hcn[p];
            const unsigned short hrb = f2bf(hrf), hcb = f2bf(hcf);
            z0[m * Z0S + jj] = hrb;
            z0[((m + 1) & 31) * Z0S + 256 + jj] = hcb;   // rolled h_col
            z1[m * Z1S + 512 + jj] = hrb;                // layer-1 x (own cols)
            z1[m * Z1S + 768 + jj] = hcb;
            rollbuf[m * 128 + jl] = hcf;
            const size_t xi = ((size_t)((t & 1) * 64 + b) * 32 + m) * 512;
            xb0[xi + jj]       = hrb;                    // publish (unrolled hcol)
            xb0[xi + 256 + jj] = hcb;
            if (t >= 31) {
                if (m == t - 31) out[OUT1 + ((size_t)(b * 2 + 0) * 32 + (t - 31)) * 256 + jj] = hrf;
                if (m == 31)     out[OUT2 + ((size_t)(b * 2 + 0) * 32 + (t - 31)) * 256 + jj] = hcf;
            }
        }
        if (tid < 256 && t + 1 < 63) {     // stage x for t+1
            const int m = tid >> 3, i = tid & 7;
            const int c = t + 1 - m;
            float v = 0.f;
            if (c >= 0 && c < 32) v = inp[((b * 32 + m) * 32 + c) * 8 + i];
            z0[m * Z0S + 512 + i] = f2bf(v);
        }
        __syncthreads();   // B2a: own writes done (s_barrier drains vmcnt)

        if (tid == 0)
            __hip_atomic_store(&f0[fown], t + 1, __ATOMIC_RELEASE, __HIP_MEMORY_SCOPE_AGENT);

        // roll readback, layer 0 (own cols)
#pragma unroll
        for (int p = 0; p < 4; ++p) {
            const int m = mh * 16 + quad * 4 + p;
            hcreg[0][p] = rollbuf[((m + 31) & 31) * 128 + jl];
        }

        // wait for partner: layer-0 images of step t, layer-1 state of step t-1
        if (tid == 0) {
            int it = 0;
            while (__hip_atomic_load(&f0[fpar], __ATOMIC_RELAXED, __HIP_MEMORY_SCOPE_AGENT) < t + 1) {
                __builtin_amdgcn_s_sleep(8);
                if (++it > 2000000) break;
            }
            it = 0;
            while (__hip_atomic_load(&f1[fpar], __ATOMIC_RELAXED, __HIP_MEMORY_SCOPE_AGENT) < t) {
                __builtin_amdgcn_s_sleep(8);
                if (++it > 2000000) break;
            }
            (void)__hip_atomic_load(&f0[fpar], __ATOMIC_ACQUIRE, __HIP_MEMORY_SCOPE_AGENT); // inv
        }
        __syncthreads();   // Bp: acquire/invalidate visible to all waves

        // partner staging: one bf16x8 per thread per buffer
        {
            const int r   = tid >> 5;            // row 0..31
            const int u   = tid & 31;
            const int reg = u >> 4;              // 0 = h_row, 1 = h_col
            const int c8  = (u & 15) * 8;
            const int col = pcol + c8;
            const int r1  = (r + 1) & 31;
            // layer-0 image (step t): z1 x-region (no roll) + z0 state (hcol rolled)
            const bf16x8 x8 = *(const bf16x8*)&xb0[((size_t)((t & 1) * 64 + b) * 32 + r) * 512 + reg * 256 + col];
            *(bf16x8*)&z1[r * Z1S + 512 + reg * 256 + col] = x8;
            *(bf16x8*)&z0[(reg ? r1 : r) * Z0S + reg * 256 + col] = x8;
            if (t > 0) {   // layer-1 state (step t-1): hcol rolled
                const bf16x8 y8 = *(const bf16x8*)&xb1[((size_t)(((t + 1) & 1) * 64 + b) * 32 + r) * 512 + reg * 256 + col];
                *(bf16x8*)&z1[(reg ? r1 : r) * Z1S + reg * 256 + col] = y8;
            }
        }
        __syncthreads();   // B2b: z1 fully staged

        // ============ phase C: GEMM1 (reads z1) + gating1 ============
#pragma unroll
        for (int G = 0; G < 6; ++G) acc[G] = (f32x4){0.f, 0.f, 0.f, 0.f};

#pragma unroll 8
        for (int ks = 0; ks < 32; ++ks) {
            const int k0 = ks * 32 + quad * 8;
            bf16x8 a0 = *(const bf16x8*)&aB1[k0];
#pragma unroll
            for (int G = 0; G < 6; ++G) {
                bf16x8 bf = *(const bf16x8*)&pW1[G][k0];
                acc[G] = __builtin_amdgcn_mfma_f32_16x16x32_bf16(a0, bf, acc[G], 0, 0, 0);
            }
        }

#pragma unroll
        for (int p = 0; p < 4; ++p) {
            const int m = mh * 16 + quad * 4 + p;
            float g0 = acc[0][p], g1 = acc[1][p], g2 = acc[2][p];
            float g3 = acc[3][p], g4 = acc[4][p], g5 = acc[5][p];
            if ((t < 32) && (m <= t)) {
                g0 += biasr[1][0]; g1 += biasr[1][1]; g2 += biasr[1][2];
                g3 += biasr[1][3]; g4 += biasr[1][4]; g5 += biasr[1][5];
            }
            const float u_r = sigm(g0), o_r = sigm(g1), u_c = sigm(g2), o_c = sigm(g3);
            const float i_r = ftanh(g4), i_c = ftanh(g5);
            const float hrp = hrreg[1][p];
            const float hcp = hcreg[1][p];
            hrreg[1][p] = ftanh((1.f - u_r) * hrp + u_r * i_r) * o_r;
            hcn[p]      = ftanh((1.f - u_c) * hcp + u_c * i_c) * o_c;
        }
        __syncthreads();   // B3: all z1 reads of step t done

        // ============ phase D: layer-1 epilogue + publish ============
#pragma unroll
        for (int p = 0; p < 4; ++p) {
            const int m  = mh * 16 + quad * 4 + p;
            const float hrf = hrreg[1][p];
            const float hcf = hcn[p];
            const unsigned short hrb = f2bf(hrf), hcb = f2bf(hcf);
            z1[m * Z1S + jj] = hrb;
            z1[((m + 1) & 31) * Z1S + 256 + jj] = hcb;
            rollbuf[m * 128 + jl] = hcf;
            const size_t xi = ((size_t)((t & 1) * 64 + b) * 32 + m) * 512;
            xb1[xi + jj]       = hrb;
            xb1[xi + 256 + jj] = hcb;                    // unrolled
            const size_t row = (size_t)(m * 64 + b);
            out[(row * 63 + t) * 512 + jj]       = hrf;  // output_all
            out[(row * 63 + t) * 512 + 256 + jj] = hcf;
            if (t >= 31) {
                if (m == t - 31) out[OUT1 + ((size_t)(b * 2 + 1) * 32 + (t - 31)) * 256 + jj] = hrf;
                if (m == 31)     out[OUT2 + ((size_t)(b * 2 + 1) * 32 + (t - 31)) * 256 + jj] = hcf;
            }
        }
        __syncthreads();   // B4: z1 state + rollbuf published (vmcnt drained)

        if (tid == 0)
            __hip_atomic_store(&f1[fown], t + 1, __ATOMIC_RELEASE, __HIP_MEMORY_SCOPE_AGENT);

#pragma unroll
        for (int p = 0; p < 4; ++p) {
            const int m = mh * 16 + quad * 4 + p;
            hcreg[1][p] = rollbuf[((m + 31) & 31) * 128 + jl];
        }
    }
}

extern "C" void kernel_launch(void* const* d_in, const int* in_sizes, int n_in,
                              void* d_out, int out_size, void* d_ws, size_t ws_size,
                              hipStream_t stream) {
    (void)in_sizes; (void)n_in; (void)out_size; (void)ws_size;
    const float* inp   = (const float*)d_in[0];   // (64,32,32,8) fp32
    const float* W0f   = (const float*)d_in[1];   // (1536,520)  fp32
    const float* W1f   = (const float*)d_in[2];   // (1,1536,1024) fp32
    const float* Biasf = (const float*)d_in[3];   // (2,1536) fp32
    float* out = (float*)d_out;

    // ws layout (13.13 MB): [W0 bf16 | W1 bf16 | flags 256 int | xb0 | xb1]
    unsigned short* Wb = (unsigned short*)d_ws;
    int* flags = (int*)(Wb + W0_ELEMS + W1_ELEMS);
    unsigned short* xb0 = (unsigned short*)(flags + 256);
    unsigned short* xb1 = xb0 + XB_ELEMS;

    convert_w<<<dim3(512), dim3(256), 0, stream>>>(W0f, W1f, Wb, flags);
    witran_coop<<<dim3(128), dim3(1024), 0, stream>>>(inp, Wb, Wb + W0_ELEMS, Biasf, out,
                                                      xb0, xb1, flags);
}

// Round 3
// 7736.049 us; speedup vs baseline: 1.3431x; 1.3431x over previous
//
#include <hip/hip_runtime.h>

typedef __bf16 bf16x8 __attribute__((ext_vector_type(8)));
typedef float  f32x4  __attribute__((ext_vector_type(4)));

#define Z0S 520   // z0 row (elems): [h_row 0:256 | h_col 256:512 | x 512:520]
#define Z1S 1032  // z1 row: [h_row | h_col | x_row 512:768 | x_col 768:1024] + 8 pad
#define W0P_ELEMS (2 * 8 * 17 * 6 * 512)   // packed W0: [s][cg][ks0..16][G][lane][8]
#define W1P_ELEMS (2 * 8 * 32 * 6 * 512)   // packed W1: [s][cg][ks0..31][G][lane][8]
#define XB_ELEMS (2 * 64 * 32 * 512)       // [slot][b][m][c] bf16, c = region*256+col

__device__ __forceinline__ unsigned short f2bf(float f) {
    unsigned int u = __builtin_bit_cast(unsigned int, f);
    u += 0x7fffu + ((u >> 16) & 1u);   // RNE
    return (unsigned short)(u >> 16);
}
__device__ __forceinline__ float sigm(float x) {
    x = fminf(30.f, fmaxf(-30.f, x));
    return __fdividef(1.0f, 1.0f + __expf(-x));
}
__device__ __forceinline__ float ftanh(float x) {
    x = fminf(15.f, fmaxf(-15.f, x));
    float e = __expf(2.0f * x);
    return 1.0f - __fdividef(2.0f, e + 1.0f);
}
__device__ __forceinline__ bf16x8 zero8() {
    bf16x8 v;
#pragma unroll
    for (int i = 0; i < 8; ++i) v[i] = (__bf16)0.0f;
    return v;
}

// fp32 -> bf16 weight conversion + MFMA-fragment packing + flag zeroing.
// Packed layout: Wp[s][cg][ks][G][lane=quad*16+l16][8] -> each wave-level
// B-fragment load is one contiguous 1 KB block (fully coalesced), vs the
// row-major layout where one load touched 64 distinct cache lines (4x L2
// line over-fetch -- the round-1/2 bottleneck).
__global__ void convert_w(const float* __restrict__ W0f, const float* __restrict__ W1f,
                          unsigned short* __restrict__ W0p, unsigned short* __restrict__ W1p,
                          int* __restrict__ flags) {
    const int gid = blockIdx.x * blockDim.x + threadIdx.x;
    const int stride = gridDim.x * blockDim.x;
    if (gid < 256) flags[gid] = 0;
    for (int i = gid; i < W0P_ELEMS; i += stride) {
        const int e = i & 7, lane = (i >> 3) & 63;
        const int r = i >> 9;
        const int G = r % 6;  const int r2 = r / 6;
        const int ks = r2 % 17; const int r3 = r2 / 17;
        const int cg = r3 & 7;  const int s = r3 >> 3;
        const int jj = s * 128 + cg * 16 + (lane & 15);
        const int k = ks * 32 + (lane >> 4) * 8 + e;
        float v = 0.f;
        if (k < 520) v = W0f[(size_t)(G * 256 + jj) * 520 + k];
        W0p[i] = f2bf(v);
    }
    for (int i = gid; i < W1P_ELEMS; i += stride) {
        const int e = i & 7, lane = (i >> 3) & 63;
        const int r = i >> 9;
        const int G = r % 6;  const int r2 = r / 6;
        const int ks = r2 & 31; const int r3 = r2 >> 5;
        const int cg = r3 & 7;  const int s = r3 >> 3;
        const int jj = s * 128 + cg * 16 + (lane & 15);
        const int k = ks * 32 + (lane >> 4) * 8 + e;
        W1p[i] = f2bf(W1f[(size_t)(G * 256 + jj) * 1024 + k]);
    }
}

// 128 blocks = 64 batches x 2 column-slices; slice s owns gate cols
// [s*128,s*128+128) -> half the weight stream per block, XCD-mapped
// (slice=(bid&7)>>2) so the 2.4 MB packed slice is L2-resident per XCD.
// Exchange protocol: publish via plain/nt stores + RELEASE flag (buffer_wbl2:
// writeback-only, weights untouched); consume via PER-ACCESS relaxed
// agent-scope atomic loads (sc0/sc1: per-access coherent, NO buffer_inv --
// round 2's acquire fence invalidated the whole per-XCD L2 every step and
// quadrupled FETCH_SIZE). Spins capped to fail loud, not hang.
__global__ __launch_bounds__(1024, 4) void witran_coop(
    const float* __restrict__ inp,             // (64,32,32,8) fp32
    const unsigned short* __restrict__ W0p,    // packed bf16
    const unsigned short* __restrict__ W1p,    // packed bf16
    const float* __restrict__ Bias,            // (2,1536)    fp32
    float* __restrict__ out,                   // fp32 outputs
    unsigned short* __restrict__ xb0,          // exchange: layer-0 images
    unsigned short* __restrict__ xb1,          // exchange: layer-1 state
    int* __restrict__ flags)                   // [128] f0 | [128] f1
{
    const int bid  = blockIdx.x;
    const int s    = (bid & 7) >> 2;                 // slice 0/1
    const int b    = (bid >> 3) * 4 + (bid & 3);     // batch 0..63
    const int ps   = 1 - s;
    const int tid  = threadIdx.x;
    const int wave = tid >> 6;                       // 0..15
    const int cg   = wave >> 1;                      // col-group 0..7
    const int mh   = wave & 1;                       // m-tile 0/1
    const int lane = tid & 63;
    const int quad = lane >> 4;
    const int l16  = lane & 15;
    const int jl   = cg * 16 + l16;                  // local col 0..127
    const int jj   = s * 128 + jl;                   // absolute col 0..255
    const int pcol = ps * 128;

    int* f0 = flags;
    int* f1 = flags + 128;
    const int fown = b * 2 + s, fpar = b * 2 + ps;

    __shared__ __align__(16) unsigned short z0[32 * Z0S];
    __shared__ __align__(16) unsigned short z1[32 * Z1S];
    __shared__ float rollbuf[32 * 128];

    for (int idx = tid; idx < 32 * Z0S; idx += 1024) z0[idx] = 0;
    for (int idx = tid; idx < 32 * Z1S; idx += 1024) z1[idx] = 0;
    __syncthreads();
    if (tid < 256) {                           // stage x for t=0
        const int m = tid >> 3, i = tid & 7;
        const int c = 0 - m;
        float v = 0.f;
        if (c >= 0 && c < 32) v = inp[((b * 32 + m) * 32 + c) * 8 + i];
        z0[m * Z0S + 512 + i] = f2bf(v);
    }

    float biasr[2][6];
#pragma unroll
    for (int L = 0; L < 2; ++L)
#pragma unroll
        for (int G = 0; G < 6; ++G)
            biasr[L][G] = Bias[L * 1536 + G * 256 + jj];

    // fp32 state: [layer][p] <-> row m = mh*16+quad*4+p, col jj
    float hrreg[2][4], hcreg[2][4], hcn[4];
#pragma unroll
    for (int L = 0; L < 2; ++L)
#pragma unroll
        for (int p = 0; p < 4; ++p) { hrreg[L][p] = 0.f; hcreg[L][p] = 0.f; }

    // wave-level packed weight bases: fragment load = contiguous 1 KB
    const unsigned short* w0w = W0p + (size_t)(s * 8 + cg) * (17 * 6 * 512) + lane * 8;
    const unsigned short* w1w = W1p + (size_t)(s * 8 + cg) * (32 * 6 * 512) + lane * 8;
    const unsigned short* aB0 = &z0[(mh * 16 + l16) * Z0S];
    const unsigned short* aB1 = &z1[(mh * 16 + l16) * Z1S];

    __syncthreads();

    const size_t OUT1 = 66060288u;           // hidden_row_all (64,2,32,256)
    const size_t OUT2 = OUT1 + 1048576u;     // hidden_col_all (64,2,32,256)

    for (int t = 0; t < 63; ++t) {
        // ============ phase A: GEMM0 (reads z0) + gating0 ============
        f32x4 acc[6];
#pragma unroll
        for (int G = 0; G < 6; ++G) acc[G] = (f32x4){0.f, 0.f, 0.f, 0.f};

#pragma unroll
        for (int ks = 0; ks < 17; ++ks) {
            bf16x8 a0;
            if (ks < 16)         a0 = *(const bf16x8*)&aB0[ks * 32 + quad * 8];
            else if (quad == 0)  a0 = *(const bf16x8*)&aB0[512];
            else                 a0 = zero8();
#pragma unroll
            for (int G = 0; G < 6; ++G) {
                bf16x8 bf = *(const bf16x8*)&w0w[(ks * 6 + G) * 512];   // B zero-padded for ks=16,quad>0
                acc[G] = __builtin_amdgcn_mfma_f32_16x16x32_bf16(a0, bf, acc[G], 0, 0, 0);
            }
        }

#pragma unroll
        for (int p = 0; p < 4; ++p) {
            const int m = mh * 16 + quad * 4 + p;
            float g0 = acc[0][p], g1 = acc[1][p], g2 = acc[2][p];
            float g3 = acc[3][p], g4 = acc[4][p], g5 = acc[5][p];
            if ((t < 32) && (m <= t)) {
                g0 += biasr[0][0]; g1 += biasr[0][1]; g2 += biasr[0][2];
                g3 += biasr[0][3]; g4 += biasr[0][4]; g5 += biasr[0][5];
            }
            const float u_r = sigm(g0), o_r = sigm(g1), u_c = sigm(g2), o_c = sigm(g3);
            const float i_r = ftanh(g4), i_c = ftanh(g5);
            const float hrp = hrreg[0][p];
            const float hcp = hcreg[0][p];
            hrreg[0][p] = ftanh((1.f - u_r) * hrp + u_r * i_r) * o_r;
            hcn[p]      = ftanh((1.f - u_c) * hcp + u_c * i_c) * o_c;
        }
        __syncthreads();   // B1: all z0 reads of step t done

        // ============ phase B: layer-0 epilogue + publish ============
#pragma unroll
        for (int p = 0; p < 4; ++p) {
            const int m  = mh * 16 + quad * 4 + p;
            const float hrf = hrreg[0][p];
            const float hcf = hcn[p];
            const unsigned short hrb = f2bf(hrf), hcb = f2bf(hcf);
            z0[m * Z0S + jj] = hrb;
            z0[((m + 1) & 31) * Z0S + 256 + jj] = hcb;   // rolled h_col
            z1[m * Z1S + 512 + jj] = hrb;                // layer-1 x (own cols)
            z1[m * Z1S + 768 + jj] = hcb;
            rollbuf[m * 128 + jl] = hcf;
            const size_t xi = ((size_t)((t & 1) * 64 + b) * 32 + m) * 512;
            __builtin_nontemporal_store(hrb, &xb0[xi + jj]);        // publish (unrolled hcol)
            __builtin_nontemporal_store(hcb, &xb0[xi + 256 + jj]);
            if (t >= 31) {
                if (m == t - 31) __builtin_nontemporal_store(hrf, &out[OUT1 + ((size_t)(b * 2 + 0) * 32 + (t - 31)) * 256 + jj]);
                if (m == 31)     __builtin_nontemporal_store(hcf, &out[OUT2 + ((size_t)(b * 2 + 0) * 32 + (t - 31)) * 256 + jj]);
            }
        }
        if (tid < 256 && t + 1 < 63) {     // stage x for t+1
            const int m = tid >> 3, i = tid & 7;
            const int c = t + 1 - m;
            float v = 0.f;
            if (c >= 0 && c < 32) v = inp[((b * 32 + m) * 32 + c) * 8 + i];
            z0[m * Z0S + 512 + i] = f2bf(v);
        }
        __syncthreads();   // B2a: own writes done (s_barrier drains vmcnt)

        if (tid == 0)
            __hip_atomic_store(&f0[fown], t + 1, __ATOMIC_RELEASE, __HIP_MEMORY_SCOPE_AGENT);

        // roll readback, layer 0 (own cols)
#pragma unroll
        for (int p = 0; p < 4; ++p) {
            const int m = mh * 16 + quad * 4 + p;
            hcreg[0][p] = rollbuf[((m + 31) & 31) * 128 + jl];
        }

        // wait for partner: layer-0 images of step t, layer-1 state of step t-1.
        // RELAXED agent loads only -- per-access coherent, no L2 invalidate.
        if (tid == 0) {
            int it = 0;
            while (__hip_atomic_load(&f0[fpar], __ATOMIC_RELAXED, __HIP_MEMORY_SCOPE_AGENT) < t + 1) {
                __builtin_amdgcn_s_sleep(4);
                if (++it > 4000000) break;
            }
            it = 0;
            while (__hip_atomic_load(&f1[fpar], __ATOMIC_RELAXED, __HIP_MEMORY_SCOPE_AGENT) < t) {
                __builtin_amdgcn_s_sleep(4);
                if (++it > 4000000) break;
            }
        }
        __syncthreads();   // Bp: partner-ready fact visible to all waves

        // partner staging via per-access agent-scope loads (fresh from IF$)
        {
            const int r   = tid >> 5;            // row 0..31
            const int u   = tid & 31;
            const int reg = u >> 4;              // 0 = h_row, 1 = h_col
            const int c8  = (u & 15) * 8;
            const int col = pcol + c8;
            const int r1  = (r + 1) & 31;
            const unsigned int* x0u = (const unsigned int*)xb0;
            const unsigned int* x1u = (const unsigned int*)xb1;
            union { unsigned int u4[4]; bf16x8 v; } q0, q1;
            const size_t e0 = (((size_t)((t & 1) * 64 + b) * 32 + r) * 512 + reg * 256 + col) >> 1;
#pragma unroll
            for (int w = 0; w < 4; ++w)
                q0.u4[w] = __hip_atomic_load(&x0u[e0 + w], __ATOMIC_RELAXED, __HIP_MEMORY_SCOPE_AGENT);
            // layer-0 image (step t): z1 x-region (no roll) + z0 state (hcol rolled)
            *(bf16x8*)&z1[r * Z1S + 512 + reg * 256 + col] = q0.v;
            *(bf16x8*)&z0[(reg ? r1 : r) * Z0S + reg * 256 + col] = q0.v;
            if (t > 0) {   // layer-1 state (step t-1): hcol rolled
                const size_t e1 = (((size_t)(((t + 1) & 1) * 64 + b) * 32 + r) * 512 + reg * 256 + col) >> 1;
#pragma unroll
                for (int w = 0; w < 4; ++w)
                    q1.u4[w] = __hip_atomic_load(&x1u[e1 + w], __ATOMIC_RELAXED, __HIP_MEMORY_SCOPE_AGENT);
                *(bf16x8*)&z1[(reg ? r1 : r) * Z1S + reg * 256 + col] = q1.v;
            }
        }
        __syncthreads();   // B2b: z1 fully staged

        // ============ phase C: GEMM1 (reads z1) + gating1 ============
#pragma unroll
        for (int G = 0; G < 6; ++G) acc[G] = (f32x4){0.f, 0.f, 0.f, 0.f};

#pragma unroll 8
        for (int ks = 0; ks < 32; ++ks) {
            bf16x8 a0 = *(const bf16x8*)&aB1[ks * 32 + quad * 8];
#pragma unroll
            for (int G = 0; G < 6; ++G) {
                bf16x8 bf = *(const bf16x8*)&w1w[(ks * 6 + G) * 512];
                acc[G] = __builtin_amdgcn_mfma_f32_16x16x32_bf16(a0, bf, acc[G], 0, 0, 0);
            }
        }

#pragma unroll
        for (int p = 0; p < 4; ++p) {
            const int m = mh * 16 + quad * 4 + p;
            float g0 = acc[0][p], g1 = acc[1][p], g2 = acc[2][p];
            float g3 = acc[3][p], g4 = acc[4][p], g5 = acc[5][p];
            if ((t < 32) && (m <= t)) {
                g0 += biasr[1][0]; g1 += biasr[1][1]; g2 += biasr[1][2];
                g3 += biasr[1][3]; g4 += biasr[1][4]; g5 += biasr[1][5];
            }
            const float u_r = sigm(g0), o_r = sigm(g1), u_c = sigm(g2), o_c = sigm(g3);
            const float i_r = ftanh(g4), i_c = ftanh(g5);
            const float hrp = hrreg[1][p];
            const float hcp = hcreg[1][p];
            hrreg[1][p] = ftanh((1.f - u_r) * hrp + u_r * i_r) * o_r;
            hcn[p]      = ftanh((1.f - u_c) * hcp + u_c * i_c) * o_c;
        }
        __syncthreads();   // B3: all z1 reads of step t done

        // ============ phase D: layer-1 epilogue + publish ============
#pragma unroll
        for (int p = 0; p < 4; ++p) {
            const int m  = mh * 16 + quad * 4 + p;
            const float hrf = hrreg[1][p];
            const float hcf = hcn[p];
            const unsigned short hrb = f2bf(hrf), hcb = f2bf(hcf);
            z1[m * Z1S + jj] = hrb;
            z1[((m + 1) & 31) * Z1S + 256 + jj] = hcb;
            rollbuf[m * 128 + jl] = hcf;
            const size_t xi = ((size_t)((t & 1) * 64 + b) * 32 + m) * 512;
            __builtin_nontemporal_store(hrb, &xb1[xi + jj]);
            __builtin_nontemporal_store(hcb, &xb1[xi + 256 + jj]);   // unrolled
            const size_t row = (size_t)(m * 64 + b);
            __builtin_nontemporal_store(hrf, &out[(row * 63 + t) * 512 + jj]);        // output_all
            __builtin_nontemporal_store(hcf, &out[(row * 63 + t) * 512 + 256 + jj]);
            if (t >= 31) {
                if (m == t - 31) __builtin_nontemporal_store(hrf, &out[OUT1 + ((size_t)(b * 2 + 1) * 32 + (t - 31)) * 256 + jj]);
                if (m == 31)     __builtin_nontemporal_store(hcf, &out[OUT2 + ((size_t)(b * 2 + 1) * 32 + (t - 31)) * 256 + jj]);
            }
        }
        __syncthreads();   // B4: z1 state + rollbuf published (vmcnt drained)

        if (tid == 0)
            __hip_atomic_store(&f1[fown], t + 1, __ATOMIC_RELEASE, __HIP_MEMORY_SCOPE_AGENT);

#pragma unroll
        for (int p = 0; p < 4; ++p) {
            const int m = mh * 16 + quad * 4 + p;
            hcreg[1][p] = rollbuf[((m + 31) & 31) * 128 + jl];
        }
    }
}

extern "C" void kernel_launch(void* const* d_in, const int* in_sizes, int n_in,
                              void* d_out, int out_size, void* d_ws, size_t ws_size,
                              hipStream_t stream) {
    (void)in_sizes; (void)n_in; (void)out_size; (void)ws_size;
    const float* inp   = (const float*)d_in[0];   // (64,32,32,8) fp32
    const float* W0f   = (const float*)d_in[1];   // (1536,520)  fp32
    const float* W1f   = (const float*)d_in[2];   // (1,1536,1024) fp32
    const float* Biasf = (const float*)d_in[3];   // (2,1536) fp32
    float* out = (float*)d_out;

    // ws layout (~13.2 MB): [W0p bf16 | W1p bf16 | flags 256 int | xb0 | xb1]
    unsigned short* W0p = (unsigned short*)d_ws;
    unsigned short* W1p = W0p + W0P_ELEMS;
    int* flags = (int*)(W1p + W1P_ELEMS);
    unsigned short* xb0 = (unsigned short*)(flags + 256);
    unsigned short* xb1 = xb0 + XB_ELEMS;

    convert_w<<<dim3(512), dim3(256), 0, stream>>>(W0f, W1f, W0p, W1p, flags);
    witran_coop<<<dim3(128), dim3(1024), 0, stream>>>(inp, W0p, W1p, Biasf, out,
                                                      xb0, xb1, flags);
}

// Round 4
// 4227.649 us; speedup vs baseline: 2.4577x; 1.8299x over previous
//
#include <hip/hip_runtime.h>

typedef __bf16 bf16x8 __attribute__((ext_vector_type(8)));
typedef float  f32x4  __attribute__((ext_vector_type(4)));

#define Z0S 520   // z0 row (elems): [h_row 0:256 | h_col 256:512 | x 512:520]
#define Z1S 1032  // z1 row: [h_row | h_col | x_row 512:768 | x_col 768:1024] + 8 pad
#define W0P_ELEMS (2 * 8 * 17 * 6 * 512)   // packed W0: [s][cg][ks0..16][G][lane][8]
#define W1P_ELEMS (2 * 8 * 32 * 6 * 512)   // packed W1: [s][cg][ks0..31][G][lane][8]
#define XB_ELEMS (2 * 64 * 32 * 512)       // [slot][b][m][c] bf16, c = region*256+col

__device__ __forceinline__ unsigned short f2bf(float f) {
    unsigned int u = __builtin_bit_cast(unsigned int, f);
    u += 0x7fffu + ((u >> 16) & 1u);   // RNE
    return (unsigned short)(u >> 16);
}
__device__ __forceinline__ float sigm(float x) {
    x = fminf(30.f, fmaxf(-30.f, x));
    return __fdividef(1.0f, 1.0f + __expf(-x));
}
__device__ __forceinline__ float ftanh(float x) {
    x = fminf(15.f, fmaxf(-15.f, x));
    float e = __expf(2.0f * x);
    return 1.0f - __fdividef(2.0f, e + 1.0f);
}
__device__ __forceinline__ bf16x8 zero8() {
    bf16x8 v;
#pragma unroll
    for (int i = 0; i < 8; ++i) v[i] = (__bf16)0.0f;
    return v;
}
// L2-bypassing stores (sc0 sc1 write-through): output/exchange streams must
// NOT allocate in L2 -- round-3 PMC showed the write streams evicting the
// L2-resident weight slice (~35% weight miss rate, 7.2 GB FETCH).
__device__ __forceinline__ void st_f32_wt(float* p, float v) {
    __hip_atomic_store(p, v, __ATOMIC_RELAXED, __HIP_MEMORY_SCOPE_AGENT);
}
__device__ __forceinline__ void st_u16_wt(unsigned short* p, unsigned short v) {
    __hip_atomic_store(p, v, __ATOMIC_RELAXED, __HIP_MEMORY_SCOPE_AGENT);
}

// fp32 -> bf16 weight conversion + MFMA-fragment packing + flag zeroing.
// Packed layout: Wp[s][cg][ks][G][lane=quad*16+l16][8] -> each wave-level
// B-fragment load is one contiguous 1 KB block (fully coalesced).
__global__ void convert_w(const float* __restrict__ W0f, const float* __restrict__ W1f,
                          unsigned short* __restrict__ W0p, unsigned short* __restrict__ W1p,
                          int* __restrict__ flags) {
    const int gid = blockIdx.x * blockDim.x + threadIdx.x;
    const int stride = gridDim.x * blockDim.x;
    if (gid < 256) flags[gid] = 0;
    for (int i = gid; i < W0P_ELEMS; i += stride) {
        const int e = i & 7, lane = (i >> 3) & 63;
        const int r = i >> 9;
        const int G = r % 6;  const int r2 = r / 6;
        const int ks = r2 % 17; const int r3 = r2 / 17;
        const int cg = r3 & 7;  const int s = r3 >> 3;
        const int jj = s * 128 + cg * 16 + (lane & 15);
        const int k = ks * 32 + (lane >> 4) * 8 + e;
        float v = 0.f;
        if (k < 520) v = W0f[(size_t)(G * 256 + jj) * 520 + k];
        W0p[i] = f2bf(v);
    }
    for (int i = gid; i < W1P_ELEMS; i += stride) {
        const int e = i & 7, lane = (i >> 3) & 63;
        const int r = i >> 9;
        const int G = r % 6;  const int r2 = r / 6;
        const int ks = r2 & 31; const int r3 = r2 >> 5;
        const int cg = r3 & 7;  const int s = r3 >> 3;
        const int jj = s * 128 + cg * 16 + (lane & 15);
        const int k = ks * 32 + (lane >> 4) * 8 + e;
        W1p[i] = f2bf(W1f[(size_t)(G * 256 + jj) * 1024 + k]);
    }
}

// 128 blocks = 64 batches x 2 column-slices; slice s owns gate cols
// [s*128,s*128+128) -> half the weight stream per block, XCD-mapped
// (slice=(bid&7)>>2) so the 2.4 MB packed slice is L2-resident per XCD.
// Exchange: publish via sc0/sc1 write-through stores + RELEASE flag; consume
// via per-access relaxed agent-scope loads (no cache-wide invalidate).
// GEMMs use double-buffered register prefetch (bA/bB, static indexing) to
// raise weight-load MLP ~6 -> ~12 within the 128-VGPR/4-wave budget.
__global__ __launch_bounds__(1024, 4) void witran_coop(
    const float* __restrict__ inp,             // (64,32,32,8) fp32
    const unsigned short* __restrict__ W0p,    // packed bf16
    const unsigned short* __restrict__ W1p,    // packed bf16
    const float* __restrict__ Bias,            // (2,1536)    fp32
    float* __restrict__ out,                   // fp32 outputs
    unsigned short* __restrict__ xb0,          // exchange: layer-0 images
    unsigned short* __restrict__ xb1,          // exchange: layer-1 state
    int* __restrict__ flags)                   // [128] f0 | [128] f1
{
    const int bid  = blockIdx.x;
    const int s    = (bid & 7) >> 2;                 // slice 0/1
    const int b    = (bid >> 3) * 4 + (bid & 3);     // batch 0..63
    const int ps   = 1 - s;
    const int tid  = threadIdx.x;
    const int wave = tid >> 6;                       // 0..15
    const int cg   = wave >> 1;                      // col-group 0..7
    const int mh   = wave & 1;                       // m-tile 0/1
    const int lane = tid & 63;
    const int quad = lane >> 4;
    const int l16  = lane & 15;
    const int jl   = cg * 16 + l16;                  // local col 0..127
    const int jj   = s * 128 + jl;                   // absolute col 0..255
    const int pcol = ps * 128;

    int* f0 = flags;
    int* f1 = flags + 128;
    const int fown = b * 2 + s, fpar = b * 2 + ps;

    __shared__ __align__(16) unsigned short z0[32 * Z0S];
    __shared__ __align__(16) unsigned short z1[32 * Z1S];
    __shared__ float rollbuf[32 * 128];

    for (int idx = tid; idx < 32 * Z0S; idx += 1024) z0[idx] = 0;
    for (int idx = tid; idx < 32 * Z1S; idx += 1024) z1[idx] = 0;
    __syncthreads();
    if (tid < 256) {                           // stage x for t=0
        const int m = tid >> 3, i = tid & 7;
        const int c = 0 - m;
        float v = 0.f;
        if (c >= 0 && c < 32) v = inp[((b * 32 + m) * 32 + c) * 8 + i];
        z0[m * Z0S + 512 + i] = f2bf(v);
    }

    float biasr[2][6];
#pragma unroll
    for (int L = 0; L < 2; ++L)
#pragma unroll
        for (int G = 0; G < 6; ++G)
            biasr[L][G] = Bias[L * 1536 + G * 256 + jj];

    // fp32 state: [layer][p] <-> row m = mh*16+quad*4+p, col jj
    float hrreg[2][4], hcreg[2][4], hcn[4];
#pragma unroll
    for (int L = 0; L < 2; ++L)
#pragma unroll
        for (int p = 0; p < 4; ++p) { hrreg[L][p] = 0.f; hcreg[L][p] = 0.f; }

    // wave-level packed weight bases: fragment load = contiguous 1 KB
    const unsigned short* w0w = W0p + (size_t)(s * 8 + cg) * (17 * 6 * 512) + lane * 8;
    const unsigned short* w1w = W1p + (size_t)(s * 8 + cg) * (32 * 6 * 512) + lane * 8;
    const unsigned short* aB0 = &z0[(mh * 16 + l16) * Z0S];
    const unsigned short* aB1 = &z1[(mh * 16 + l16) * Z1S];

    __syncthreads();

    const size_t OUT1 = 66060288u;           // hidden_row_all (64,2,32,256)
    const size_t OUT2 = OUT1 + 1048576u;     // hidden_col_all (64,2,32,256)

    for (int t = 0; t < 63; ++t) {
        // ============ phase A: GEMM0 (reads z0) + gating0 ============
        f32x4 acc[6];
        bf16x8 bA[6], bB[6];
#pragma unroll
        for (int G = 0; G < 6; ++G) acc[G] = (f32x4){0.f, 0.f, 0.f, 0.f};
#pragma unroll
        for (int G = 0; G < 6; ++G) bA[G] = *(const bf16x8*)&w0w[G * 512];

#pragma unroll 4
        for (int kp = 0; kp < 8; ++kp) {
            bf16x8 a0 = *(const bf16x8*)&aB0[(2 * kp) * 32 + quad * 8];
            bf16x8 a1 = *(const bf16x8*)&aB0[(2 * kp + 1) * 32 + quad * 8];
#pragma unroll
            for (int G = 0; G < 6; ++G) bB[G] = *(const bf16x8*)&w0w[((2 * kp + 1) * 6 + G) * 512];
#pragma unroll
            for (int G = 0; G < 6; ++G)
                acc[G] = __builtin_amdgcn_mfma_f32_16x16x32_bf16(a0, bA[G], acc[G], 0, 0, 0);
#pragma unroll
            for (int G = 0; G < 6; ++G) bA[G] = *(const bf16x8*)&w0w[((2 * kp + 2) * 6 + G) * 512];
#pragma unroll
            for (int G = 0; G < 6; ++G)
                acc[G] = __builtin_amdgcn_mfma_f32_16x16x32_bf16(a1, bB[G], acc[G], 0, 0, 0);
        }
        {   // ks=16 partial (in bA): x cols 512..519 on quad 0; B zero-padded
            bf16x8 a0 = zero8();
            if (quad == 0) a0 = *(const bf16x8*)&aB0[512];
#pragma unroll
            for (int G = 0; G < 6; ++G)
                acc[G] = __builtin_amdgcn_mfma_f32_16x16x32_bf16(a0, bA[G], acc[G], 0, 0, 0);
        }

#pragma unroll
        for (int p = 0; p < 4; ++p) {
            const int m = mh * 16 + quad * 4 + p;
            float g0 = acc[0][p], g1 = acc[1][p], g2 = acc[2][p];
            float g3 = acc[3][p], g4 = acc[4][p], g5 = acc[5][p];
            if ((t < 32) && (m <= t)) {
                g0 += biasr[0][0]; g1 += biasr[0][1]; g2 += biasr[0][2];
                g3 += biasr[0][3]; g4 += biasr[0][4]; g5 += biasr[0][5];
            }
            const float u_r = sigm(g0), o_r = sigm(g1), u_c = sigm(g2), o_c = sigm(g3);
            const float i_r = ftanh(g4), i_c = ftanh(g5);
            const float hrp = hrreg[0][p];
            const float hcp = hcreg[0][p];
            hrreg[0][p] = ftanh((1.f - u_r) * hrp + u_r * i_r) * o_r;
            hcn[p]      = ftanh((1.f - u_c) * hcp + u_c * i_c) * o_c;
        }
        __syncthreads();   // B1: all z0 reads of step t done

        // ============ phase B: layer-0 epilogue + publish ============
#pragma unroll
        for (int p = 0; p < 4; ++p) {
            const int m  = mh * 16 + quad * 4 + p;
            const float hrf = hrreg[0][p];
            const float hcf = hcn[p];
            const unsigned short hrb = f2bf(hrf), hcb = f2bf(hcf);
            z0[m * Z0S + jj] = hrb;
            z0[((m + 1) & 31) * Z0S + 256 + jj] = hcb;   // rolled h_col
            z1[m * Z1S + 512 + jj] = hrb;                // layer-1 x (own cols)
            z1[m * Z1S + 768 + jj] = hcb;
            rollbuf[m * 128 + jl] = hcf;
            const size_t xi = ((size_t)((t & 1) * 64 + b) * 32 + m) * 512;
            st_u16_wt(&xb0[xi + jj], hrb);               // publish (unrolled hcol)
            st_u16_wt(&xb0[xi + 256 + jj], hcb);
            if (t >= 31) {
                if (m == t - 31) st_f32_wt(&out[OUT1 + ((size_t)(b * 2 + 0) * 32 + (t - 31)) * 256 + jj], hrf);
                if (m == 31)     st_f32_wt(&out[OUT2 + ((size_t)(b * 2 + 0) * 32 + (t - 31)) * 256 + jj], hcf);
            }
        }
        if (tid < 256 && t + 1 < 63) {     // stage x for t+1
            const int m = tid >> 3, i = tid & 7;
            const int c = t + 1 - m;
            float v = 0.f;
            if (c >= 0 && c < 32) v = inp[((b * 32 + m) * 32 + c) * 8 + i];
            z0[m * Z0S + 512 + i] = f2bf(v);
        }
        __syncthreads();   // B2a: own writes done (s_barrier drains vmcnt)

        if (tid == 0)
            __hip_atomic_store(&f0[fown], t + 1, __ATOMIC_RELEASE, __HIP_MEMORY_SCOPE_AGENT);

        // roll readback, layer 0 (own cols)
#pragma unroll
        for (int p = 0; p < 4; ++p) {
            const int m = mh * 16 + quad * 4 + p;
            hcreg[0][p] = rollbuf[((m + 31) & 31) * 128 + jl];
        }

        // wait for partner: layer-0 images of step t, layer-1 state of step t-1.
        // RELAXED agent loads only -- per-access coherent, no L2 invalidate.
        if (tid == 0) {
            int it = 0;
            while (__hip_atomic_load(&f0[fpar], __ATOMIC_RELAXED, __HIP_MEMORY_SCOPE_AGENT) < t + 1) {
                __builtin_amdgcn_s_sleep(4);
                if (++it > 4000000) break;
            }
            it = 0;
            while (__hip_atomic_load(&f1[fpar], __ATOMIC_RELAXED, __HIP_MEMORY_SCOPE_AGENT) < t) {
                __builtin_amdgcn_s_sleep(4);
                if (++it > 4000000) break;
            }
        }
        __syncthreads();   // Bp: partner-ready fact visible to all waves

        // partner staging via per-access agent-scope loads (fresh from IF$)
        {
            const int r   = tid >> 5;            // row 0..31
            const int u   = tid & 31;
            const int reg = u >> 4;              // 0 = h_row, 1 = h_col
            const int c8  = (u & 15) * 8;
            const int col = pcol + c8;
            const int r1  = (r + 1) & 31;
            const unsigned int* x0u = (const unsigned int*)xb0;
            const unsigned int* x1u = (const unsigned int*)xb1;
            union { unsigned int u4[4]; bf16x8 v; } q0, q1;
            const size_t e0 = (((size_t)((t & 1) * 64 + b) * 32 + r) * 512 + reg * 256 + col) >> 1;
#pragma unroll
            for (int w = 0; w < 4; ++w)
                q0.u4[w] = __hip_atomic_load(&x0u[e0 + w], __ATOMIC_RELAXED, __HIP_MEMORY_SCOPE_AGENT);
            // layer-0 image (step t): z1 x-region (no roll) + z0 state (hcol rolled)
            *(bf16x8*)&z1[r * Z1S + 512 + reg * 256 + col] = q0.v;
            *(bf16x8*)&z0[(reg ? r1 : r) * Z0S + reg * 256 + col] = q0.v;
            if (t > 0) {   // layer-1 state (step t-1): hcol rolled
                const size_t e1 = (((size_t)(((t + 1) & 1) * 64 + b) * 32 + r) * 512 + reg * 256 + col) >> 1;
#pragma unroll
                for (int w = 0; w < 4; ++w)
                    q1.u4[w] = __hip_atomic_load(&x1u[e1 + w], __ATOMIC_RELAXED, __HIP_MEMORY_SCOPE_AGENT);
                *(bf16x8*)&z1[(reg ? r1 : r) * Z1S + reg * 256 + col] = q1.v;
            }
        }
        __syncthreads();   // B2b: z1 fully staged

        // ============ phase C: GEMM1 (reads z1) + gating1 ============
#pragma unroll
        for (int G = 0; G < 6; ++G) acc[G] = (f32x4){0.f, 0.f, 0.f, 0.f};
#pragma unroll
        for (int G = 0; G < 6; ++G) bA[G] = *(const bf16x8*)&w1w[G * 512];

#pragma unroll 4
        for (int kp = 0; kp < 16; ++kp) {
            bf16x8 a0 = *(const bf16x8*)&aB1[(2 * kp) * 32 + quad * 8];
            bf16x8 a1 = *(const bf16x8*)&aB1[(2 * kp + 1) * 32 + quad * 8];
#pragma unroll
            for (int G = 0; G < 6; ++G) bB[G] = *(const bf16x8*)&w1w[((2 * kp + 1) * 6 + G) * 512];
#pragma unroll
            for (int G = 0; G < 6; ++G)
                acc[G] = __builtin_amdgcn_mfma_f32_16x16x32_bf16(a0, bA[G], acc[G], 0, 0, 0);
            const int kn = (kp < 15) ? (2 * kp + 2) : 31;   // clamp: last prefetch redundant
#pragma unroll
            for (int G = 0; G < 6; ++G) bA[G] = *(const bf16x8*)&w1w[(kn * 6 + G) * 512];
#pragma unroll
            for (int G = 0; G < 6; ++G)
                acc[G] = __builtin_amdgcn_mfma_f32_16x16x32_bf16(a1, bB[G], acc[G], 0, 0, 0);
        }

#pragma unroll
        for (int p = 0; p < 4; ++p) {
            const int m = mh * 16 + quad * 4 + p;
            float g0 = acc[0][p], g1 = acc[1][p], g2 = acc[2][p];
            float g3 = acc[3][p], g4 = acc[4][p], g5 = acc[5][p];
            if ((t < 32) && (m <= t)) {
                g0 += biasr[1][0]; g1 += biasr[1][1]; g2 += biasr[1][2];
                g3 += biasr[1][3]; g4 += biasr[1][4]; g5 += biasr[1][5];
            }
            const float u_r = sigm(g0), o_r = sigm(g1), u_c = sigm(g2), o_c = sigm(g3);
            const float i_r = ftanh(g4), i_c = ftanh(g5);
            const float hrp = hrreg[1][p];
            const float hcp = hcreg[1][p];
            hrreg[1][p] = ftanh((1.f - u_r) * hrp + u_r * i_r) * o_r;
            hcn[p]      = ftanh((1.f - u_c) * hcp + u_c * i_c) * o_c;
        }
        __syncthreads();   // B3: all z1 reads of step t done

        // ============ phase D: layer-1 epilogue + publish ============
#pragma unroll
        for (int p = 0; p < 4; ++p) {
            const int m  = mh * 16 + quad * 4 + p;
            const float hrf = hrreg[1][p];
            const float hcf = hcn[p];
            const unsigned short hrb = f2bf(hrf), hcb = f2bf(hcf);
            z1[m * Z1S + jj] = hrb;
            z1[((m + 1) & 31) * Z1S + 256 + jj] = hcb;
            rollbuf[m * 128 + jl] = hcf;
            const size_t xi = ((size_t)((t & 1) * 64 + b) * 32 + m) * 512;
            st_u16_wt(&xb1[xi + jj], hrb);
            st_u16_wt(&xb1[xi + 256 + jj], hcb);         // unrolled
            const size_t row = (size_t)(m * 64 + b);
            st_f32_wt(&out[(row * 63 + t) * 512 + jj], hrf);        // output_all
            st_f32_wt(&out[(row * 63 + t) * 512 + 256 + jj], hcf);
            if (t >= 31) {
                if (m == t - 31) st_f32_wt(&out[OUT1 + ((size_t)(b * 2 + 1) * 32 + (t - 31)) * 256 + jj], hrf);
                if (m == 31)     st_f32_wt(&out[OUT2 + ((size_t)(b * 2 + 1) * 32 + (t - 31)) * 256 + jj], hcf);
            }
        }
        __syncthreads();   // B4: z1 state + rollbuf published (vmcnt drained)

        if (tid == 0)
            __hip_atomic_store(&f1[fown], t + 1, __ATOMIC_RELEASE, __HIP_MEMORY_SCOPE_AGENT);

#pragma unroll
        for (int p = 0; p < 4; ++p) {
            const int m = mh * 16 + quad * 4 + p;
            hcreg[1][p] = rollbuf[((m + 31) & 31) * 128 + jl];
        }
    }
}

extern "C" void kernel_launch(void* const* d_in, const int* in_sizes, int n_in,
                              void* d_out, int out_size, void* d_ws, size_t ws_size,
                              hipStream_t stream) {
    (void)in_sizes; (void)n_in; (void)out_size; (void)ws_size;
    const float* inp   = (const float*)d_in[0];   // (64,32,32,8) fp32
    const float* W0f   = (const float*)d_in[1];   // (1536,520)  fp32
    const float* W1f   = (const float*)d_in[2];   // (1,1536,1024) fp32
    const float* Biasf = (const float*)d_in[3];   // (2,1536) fp32
    float* out = (float*)d_out;

    // ws layout (~13.2 MB): [W0p bf16 | W1p bf16 | flags 256 int | xb0 | xb1]
    unsigned short* W0p = (unsigned short*)d_ws;
    unsigned short* W1p = W0p + W0P_ELEMS;
    int* flags = (int*)(W1p + W1P_ELEMS);
    unsigned short* xb0 = (unsigned short*)(flags + 256);
    unsigned short* xb1 = xb0 + XB_ELEMS;

    convert_w<<<dim3(512), dim3(256), 0, stream>>>(W0f, W1f, W0p, W1p, flags);
    witran_coop<<<dim3(128), dim3(1024), 0, stream>>>(inp, W0p, W1p, Biasf, out,
                                                      xb0, xb1, flags);
}

// Round 5
// 2211.352 us; speedup vs baseline: 4.6986x; 1.9118x over previous
//
#include <hip/hip_runtime.h>

typedef __bf16 bf16x8 __attribute__((ext_vector_type(8)));
typedef float  f32x4  __attribute__((ext_vector_type(4)));

#define Z0S 520   // z0 row (elems): [h_row 0:256 | h_col 256:512 | x 512:520]
#define Z1S 1032  // z1 row: [h_row | h_col | x_row 512:768 | x_col 768:1024] + 8 pad
#define W0P_ELEMS (2 * 8 * 17 * 6 * 512)   // packed W0: [gcg 0..15][ks0..16][G][lane][8]
#define W1P_ELEMS (2 * 8 * 32 * 6 * 512)   // packed W1: [gcg 0..15][ks0..31][G][lane][8]
#define XB_ELEMS (2 * 64 * 32 * 512)       // [slot][b][m][c] bf16, c = region*256+col

__device__ __forceinline__ unsigned short f2bf(float f) {
    unsigned int u = __builtin_bit_cast(unsigned int, f);
    u += 0x7fffu + ((u >> 16) & 1u);   // RNE
    return (unsigned short)(u >> 16);
}
__device__ __forceinline__ float sigm(float x) {
    x = fminf(30.f, fmaxf(-30.f, x));
    return __fdividef(1.0f, 1.0f + __expf(-x));
}
__device__ __forceinline__ float ftanh(float x) {
    x = fminf(15.f, fmaxf(-15.f, x));
    float e = __expf(2.0f * x);
    return 1.0f - __fdividef(2.0f, e + 1.0f);
}
__device__ __forceinline__ bf16x8 zero8() {
    bf16x8 v;
#pragma unroll
    for (int i = 0; i < 8; ++i) v[i] = (__bf16)0.0f;
    return v;
}
// L2-bypassing stores (write-through): output/exchange streams must NOT
// allocate in L2 -- round-3 PMC showed write streams evicting the weight
// slice; round-4 confirmed (FETCH 7.2 -> 2.2 GB, dur -45%).
__device__ __forceinline__ void st_f32_wt(float* p, float v) {
    __hip_atomic_store(p, v, __ATOMIC_RELAXED, __HIP_MEMORY_SCOPE_AGENT);
}
__device__ __forceinline__ void st_u16_wt(unsigned short* p, unsigned short v) {
    __hip_atomic_store(p, v, __ATOMIC_RELAXED, __HIP_MEMORY_SCOPE_AGENT);
}

// fp32 -> bf16 weight conversion + MFMA-fragment packing + flag zeroing.
// Packed layout: Wp[gcg=jj>>4][ks][G][lane=quad*16+l16][8] -> each wave-level
// B-fragment load is one contiguous 1 KB block (fully coalesced).
__global__ void convert_w(const float* __restrict__ W0f, const float* __restrict__ W1f,
                          unsigned short* __restrict__ W0p, unsigned short* __restrict__ W1p,
                          int* __restrict__ flags) {
    const int gid = blockIdx.x * blockDim.x + threadIdx.x;
    const int stride = gridDim.x * blockDim.x;
    if (gid < 512) flags[gid] = 0;
    for (int i = gid; i < W0P_ELEMS; i += stride) {
        const int e = i & 7, lane = (i >> 3) & 63;
        const int r = i >> 9;
        const int G = r % 6;  const int r2 = r / 6;
        const int ks = r2 % 17; const int gcg = r2 / 17;    // 0..15
        const int jj = gcg * 16 + (lane & 15);
        const int k = ks * 32 + (lane >> 4) * 8 + e;
        float v = 0.f;
        if (k < 520) v = W0f[(size_t)(G * 256 + jj) * 520 + k];
        W0p[i] = f2bf(v);
    }
    for (int i = gid; i < W1P_ELEMS; i += stride) {
        const int e = i & 7, lane = (i >> 3) & 63;
        const int r = i >> 9;
        const int G = r % 6;  const int r2 = r / 6;
        const int ks = r2 & 31; const int gcg = r2 >> 5;    // 0..15
        const int jj = gcg * 16 + (lane & 15);
        const int k = ks * 32 + (lane >> 4) * 8 + e;
        W1p[i] = f2bf(W1f[(size_t)(G * 256 + jj) * 1024 + k]);
    }
}

// 256 blocks = 64 batches x 4 column-slices (64 cols each); 512 threads =
// 8 waves = 4 col-groups x 2 m-tiles. Rationale (round 5): round-4 was
// L1-delivery-bound -- 4.7 MB/step of weight fragments through each of only
// 128 CUs' 64 B/cy L1 port (30.6 us/step floor). Splitting 4-way puts all
// 256 CUs to work: 2.35 MB/step/CU (15.3 us floor) and a 1.18 MB per-XCD
// weight set (slice = (bid&7)>>1 -> XCD pair per slice, ample L2 headroom).
// Exchange generalizes to 3 partner slices; protocol (write-through publish,
// relaxed agent-scope flag/data loads, no cache-wide invalidate) unchanged.
// 256 blocks x 1 block/CU (105 KB LDS) = exactly co-resident; spins capped.
__global__ __launch_bounds__(512, 2) void witran_coop(
    const float* __restrict__ inp,             // (64,32,32,8) fp32
    const unsigned short* __restrict__ W0p,    // packed bf16
    const unsigned short* __restrict__ W1p,    // packed bf16
    const float* __restrict__ Bias,            // (2,1536)    fp32
    float* __restrict__ out,                   // fp32 outputs
    unsigned short* __restrict__ xb0,          // exchange: layer-0 images
    unsigned short* __restrict__ xb1,          // exchange: layer-1 state
    int* __restrict__ flags)                   // [256] f0 | [256] f1
{
    const int bid  = blockIdx.x;
    const int r8   = bid & 7;
    const int s    = r8 >> 1;                        // slice 0..3 (XCD pair)
    const int b    = (bid >> 3) * 2 + (r8 & 1);      // batch 0..63
    const int tid  = threadIdx.x;
    const int wave = tid >> 6;                       // 0..7
    const int cg   = wave >> 1;                      // col-group 0..3
    const int mh   = wave & 1;                       // m-tile 0/1
    const int lane = tid & 63;
    const int quad = lane >> 4;
    const int l16  = lane & 15;
    const int jl   = cg * 16 + l16;                  // local col 0..63
    const int jj   = s * 64 + jl;                    // absolute col 0..255
    const int gcg  = jj >> 4;                        // global col-group 0..15

    int* f0 = flags;
    int* f1 = flags + 256;
    const int fown = b * 4 + s;

    __shared__ __align__(16) unsigned short z0[32 * Z0S];
    __shared__ __align__(16) unsigned short z1[32 * Z1S];
    __shared__ float rollbuf[32 * 64];

    for (int idx = tid; idx < 32 * Z0S; idx += 512) z0[idx] = 0;
    for (int idx = tid; idx < 32 * Z1S; idx += 512) z1[idx] = 0;
    __syncthreads();
    if (tid < 256) {                           // stage x for t=0
        const int m = tid >> 3, i = tid & 7;
        const int c = 0 - m;
        float v = 0.f;
        if (c >= 0 && c < 32) v = inp[((b * 32 + m) * 32 + c) * 8 + i];
        z0[m * Z0S + 512 + i] = f2bf(v);
    }

    float biasr[2][6];
#pragma unroll
    for (int L = 0; L < 2; ++L)
#pragma unroll
        for (int G = 0; G < 6; ++G)
            biasr[L][G] = Bias[L * 1536 + G * 256 + jj];

    // fp32 state: [layer][p] <-> row m = mh*16+quad*4+p, col jj
    float hrreg[2][4], hcreg[2][4], hcn[4];
#pragma unroll
    for (int L = 0; L < 2; ++L)
#pragma unroll
        for (int p = 0; p < 4; ++p) { hrreg[L][p] = 0.f; hcreg[L][p] = 0.f; }

    // wave-level packed weight bases: fragment load = contiguous 1 KB
    const unsigned short* w0w = W0p + (size_t)gcg * (17 * 6 * 512) + lane * 8;
    const unsigned short* w1w = W1p + (size_t)gcg * (32 * 6 * 512) + lane * 8;
    const unsigned short* aB0 = &z0[(mh * 16 + l16) * Z0S];
    const unsigned short* aB1 = &z1[(mh * 16 + l16) * Z1S];

    __syncthreads();

    const size_t OUT1 = 66060288u;           // hidden_row_all (64,2,32,256)
    const size_t OUT2 = OUT1 + 1048576u;     // hidden_col_all (64,2,32,256)

    // partner-staging decomposition: 512 threads = 32 rows x 2 regions x 8 chunks
    const int sr   = tid >> 4;               // row 0..31
    const int srem = tid & 15;
    const int sreg = srem >> 3;              // 0 = h_row, 1 = h_col
    const int sc8  = (srem & 7) * 8;         // chunk offset within 64-col slice
    const int sr1  = (sr + 1) & 31;

    for (int t = 0; t < 63; ++t) {
        // ============ phase A: GEMM0 (reads z0) + gating0 ============
        f32x4 acc[6];
        bf16x8 bA[6], bB[6];
#pragma unroll
        for (int G = 0; G < 6; ++G) acc[G] = (f32x4){0.f, 0.f, 0.f, 0.f};
#pragma unroll
        for (int G = 0; G < 6; ++G) bA[G] = *(const bf16x8*)&w0w[G * 512];

#pragma unroll 4
        for (int kp = 0; kp < 8; ++kp) {
            bf16x8 a0 = *(const bf16x8*)&aB0[(2 * kp) * 32 + quad * 8];
            bf16x8 a1 = *(const bf16x8*)&aB0[(2 * kp + 1) * 32 + quad * 8];
#pragma unroll
            for (int G = 0; G < 6; ++G) bB[G] = *(const bf16x8*)&w0w[((2 * kp + 1) * 6 + G) * 512];
#pragma unroll
            for (int G = 0; G < 6; ++G)
                acc[G] = __builtin_amdgcn_mfma_f32_16x16x32_bf16(a0, bA[G], acc[G], 0, 0, 0);
#pragma unroll
            for (int G = 0; G < 6; ++G) bA[G] = *(const bf16x8*)&w0w[((2 * kp + 2) * 6 + G) * 512];
#pragma unroll
            for (int G = 0; G < 6; ++G)
                acc[G] = __builtin_amdgcn_mfma_f32_16x16x32_bf16(a1, bB[G], acc[G], 0, 0, 0);
        }
        {   // ks=16 partial (in bA): x cols 512..519 on quad 0; B zero-padded
            bf16x8 a0 = zero8();
            if (quad == 0) a0 = *(const bf16x8*)&aB0[512];
#pragma unroll
            for (int G = 0; G < 6; ++G)
                acc[G] = __builtin_amdgcn_mfma_f32_16x16x32_bf16(a0, bA[G], acc[G], 0, 0, 0);
        }

#pragma unroll
        for (int p = 0; p < 4; ++p) {
            const int m = mh * 16 + quad * 4 + p;
            float g0 = acc[0][p], g1 = acc[1][p], g2 = acc[2][p];
            float g3 = acc[3][p], g4 = acc[4][p], g5 = acc[5][p];
            if ((t < 32) && (m <= t)) {
                g0 += biasr[0][0]; g1 += biasr[0][1]; g2 += biasr[0][2];
                g3 += biasr[0][3]; g4 += biasr[0][4]; g5 += biasr[0][5];
            }
            const float u_r = sigm(g0), o_r = sigm(g1), u_c = sigm(g2), o_c = sigm(g3);
            const float i_r = ftanh(g4), i_c = ftanh(g5);
            const float hrp = hrreg[0][p];
            const float hcp = hcreg[0][p];
            hrreg[0][p] = ftanh((1.f - u_r) * hrp + u_r * i_r) * o_r;
            hcn[p]      = ftanh((1.f - u_c) * hcp + u_c * i_c) * o_c;
        }
        __syncthreads();   // B1: all z0 reads of step t done

        // ============ phase B: layer-0 epilogue + publish ============
#pragma unroll
        for (int p = 0; p < 4; ++p) {
            const int m  = mh * 16 + quad * 4 + p;
            const float hrf = hrreg[0][p];
            const float hcf = hcn[p];
            const unsigned short hrb = f2bf(hrf), hcb = f2bf(hcf);
            z0[m * Z0S + jj] = hrb;
            z0[((m + 1) & 31) * Z0S + 256 + jj] = hcb;   // rolled h_col
            z1[m * Z1S + 512 + jj] = hrb;                // layer-1 x (own cols)
            z1[m * Z1S + 768 + jj] = hcb;
            rollbuf[m * 64 + jl] = hcf;
            const size_t xi = ((size_t)((t & 1) * 64 + b) * 32 + m) * 512;
            st_u16_wt(&xb0[xi + jj], hrb);               // publish (unrolled hcol)
            st_u16_wt(&xb0[xi + 256 + jj], hcb);
            if (t >= 31) {
                if (m == t - 31) st_f32_wt(&out[OUT1 + ((size_t)(b * 2 + 0) * 32 + (t - 31)) * 256 + jj], hrf);
                if (m == 31)     st_f32_wt(&out[OUT2 + ((size_t)(b * 2 + 0) * 32 + (t - 31)) * 256 + jj], hcf);
            }
        }
        if (tid < 256 && t + 1 < 63) {     // stage x for t+1
            const int m = tid >> 3, i = tid & 7;
            const int c = t + 1 - m;
            float v = 0.f;
            if (c >= 0 && c < 32) v = inp[((b * 32 + m) * 32 + c) * 8 + i];
            z0[m * Z0S + 512 + i] = f2bf(v);
        }
        __syncthreads();   // B2a: own writes done (s_barrier drains vmcnt)

        if (tid == 0)
            __hip_atomic_store(&f0[fown], t + 1, __ATOMIC_RELEASE, __HIP_MEMORY_SCOPE_AGENT);

        // roll readback, layer 0 (own cols)
#pragma unroll
        for (int p = 0; p < 4; ++p) {
            const int m = mh * 16 + quad * 4 + p;
            hcreg[0][p] = rollbuf[((m + 31) & 31) * 64 + jl];
        }

        // wait for 3 partner slices: layer-0 step t, layer-1 step t-1.
        // RELAXED agent loads only -- per-access coherent, no L2 invalidate.
        if (tid == 0) {
#pragma unroll
            for (int j = 1; j < 4; ++j) {
                const int fp = b * 4 + ((s + j) & 3);
                int it = 0;
                while (__hip_atomic_load(&f0[fp], __ATOMIC_RELAXED, __HIP_MEMORY_SCOPE_AGENT) < t + 1) {
                    __builtin_amdgcn_s_sleep(4);
                    if (++it > 4000000) break;
                }
                it = 0;
                while (__hip_atomic_load(&f1[fp], __ATOMIC_RELAXED, __HIP_MEMORY_SCOPE_AGENT) < t) {
                    __builtin_amdgcn_s_sleep(4);
                    if (++it > 4000000) break;
                }
            }
        }
        __syncthreads();   // Bp: partner-ready fact visible to all waves

        // partner staging: one 16 B chunk per partner slice per buffer per thread
        {
            const unsigned int* x0u = (const unsigned int*)xb0;
            const unsigned int* x1u = (const unsigned int*)xb1;
#pragma unroll
            for (int j = 1; j < 4; ++j) {
                const int q   = (s + j) & 3;
                const int col = q * 64 + sc8;
                union { unsigned int u4[4]; bf16x8 v; } q0, q1;
                const size_t e0 = (((size_t)((t & 1) * 64 + b) * 32 + sr) * 512 + sreg * 256 + col) >> 1;
#pragma unroll
                for (int w = 0; w < 4; ++w)
                    q0.u4[w] = __hip_atomic_load(&x0u[e0 + w], __ATOMIC_RELAXED, __HIP_MEMORY_SCOPE_AGENT);
                // layer-0 image (step t): z1 x-region (no roll) + z0 state (hcol rolled)
                *(bf16x8*)&z1[sr * Z1S + 512 + sreg * 256 + col] = q0.v;
                *(bf16x8*)&z0[(sreg ? sr1 : sr) * Z0S + sreg * 256 + col] = q0.v;
                if (t > 0) {   // layer-1 state (step t-1): hcol rolled
                    const size_t e1 = (((size_t)(((t + 1) & 1) * 64 + b) * 32 + sr) * 512 + sreg * 256 + col) >> 1;
#pragma unroll
                    for (int w = 0; w < 4; ++w)
                        q1.u4[w] = __hip_atomic_load(&x1u[e1 + w], __ATOMIC_RELAXED, __HIP_MEMORY_SCOPE_AGENT);
                    *(bf16x8*)&z1[(sreg ? sr1 : sr) * Z1S + sreg * 256 + col] = q1.v;
                }
            }
        }
        __syncthreads();   // B2b: z1 fully staged

        // ============ phase C: GEMM1 (reads z1) + gating1 ============
#pragma unroll
        for (int G = 0; G < 6; ++G) acc[G] = (f32x4){0.f, 0.f, 0.f, 0.f};
#pragma unroll
        for (int G = 0; G < 6; ++G) bA[G] = *(const bf16x8*)&w1w[G * 512];

#pragma unroll 4
        for (int kp = 0; kp < 16; ++kp) {
            bf16x8 a0 = *(const bf16x8*)&aB1[(2 * kp) * 32 + quad * 8];
            bf16x8 a1 = *(const bf16x8*)&aB1[(2 * kp + 1) * 32 + quad * 8];
#pragma unroll
            for (int G = 0; G < 6; ++G) bB[G] = *(const bf16x8*)&w1w[((2 * kp + 1) * 6 + G) * 512];
#pragma unroll
            for (int G = 0; G < 6; ++G)
                acc[G] = __builtin_amdgcn_mfma_f32_16x16x32_bf16(a0, bA[G], acc[G], 0, 0, 0);
            const int kn = (kp < 15) ? (2 * kp + 2) : 31;   // clamp: last prefetch redundant
#pragma unroll
            for (int G = 0; G < 6; ++G) bA[G] = *(const bf16x8*)&w1w[(kn * 6 + G) * 512];
#pragma unroll
            for (int G = 0; G < 6; ++G)
                acc[G] = __builtin_amdgcn_mfma_f32_16x16x32_bf16(a1, bB[G], acc[G], 0, 0, 0);
        }

#pragma unroll
        for (int p = 0; p < 4; ++p) {
            const int m = mh * 16 + quad * 4 + p;
            float g0 = acc[0][p], g1 = acc[1][p], g2 = acc[2][p];
            float g3 = acc[3][p], g4 = acc[4][p], g5 = acc[5][p];
            if ((t < 32) && (m <= t)) {
                g0 += biasr[1][0]; g1 += biasr[1][1]; g2 += biasr[1][2];
                g3 += biasr[1][3]; g4 += biasr[1][4]; g5 += biasr[1][5];
            }
            const float u_r = sigm(g0), o_r = sigm(g1), u_c = sigm(g2), o_c = sigm(g3);
            const float i_r = ftanh(g4), i_c = ftanh(g5);
            const float hrp = hrreg[1][p];
            const float hcp = hcreg[1][p];
            hrreg[1][p] = ftanh((1.f - u_r) * hrp + u_r * i_r) * o_r;
            hcn[p]      = ftanh((1.f - u_c) * hcp + u_c * i_c) * o_c;
        }
        __syncthreads();   // B3: all z1 reads of step t done

        // ============ phase D: layer-1 epilogue + publish ============
#pragma unroll
        for (int p = 0; p < 4; ++p) {
            const int m  = mh * 16 + quad * 4 + p;
            const float hrf = hrreg[1][p];
            const float hcf = hcn[p];
            const unsigned short hrb = f2bf(hrf), hcb = f2bf(hcf);
            z1[m * Z1S + jj] = hrb;
            z1[((m + 1) & 31) * Z1S + 256 + jj] = hcb;
            rollbuf[m * 64 + jl] = hcf;
            const size_t xi = ((size_t)((t & 1) * 64 + b) * 32 + m) * 512;
            st_u16_wt(&xb1[xi + jj], hrb);
            st_u16_wt(&xb1[xi + 256 + jj], hcb);         // unrolled
            const size_t row = (size_t)(m * 64 + b);
            st_f32_wt(&out[(row * 63 + t) * 512 + jj], hrf);        // output_all
            st_f32_wt(&out[(row * 63 + t) * 512 + 256 + jj], hcf);
            if (t >= 31) {
                if (m == t - 31) st_f32_wt(&out[OUT1 + ((size_t)(b * 2 + 1) * 32 + (t - 31)) * 256 + jj], hrf);
                if (m == 31)     st_f32_wt(&out[OUT2 + ((size_t)(b * 2 + 1) * 32 + (t - 31)) * 256 + jj], hcf);
            }
        }
        __syncthreads();   // B4: z1 state + rollbuf published (vmcnt drained)

        if (tid == 0)
            __hip_atomic_store(&f1[fown], t + 1, __ATOMIC_RELEASE, __HIP_MEMORY_SCOPE_AGENT);

#pragma unroll
        for (int p = 0; p < 4; ++p) {
            const int m = mh * 16 + quad * 4 + p;
            hcreg[1][p] = rollbuf[((m + 31) & 31) * 64 + jl];
        }
    }
}

extern "C" void kernel_launch(void* const* d_in, const int* in_sizes, int n_in,
                              void* d_out, int out_size, void* d_ws, size_t ws_size,
                              hipStream_t stream) {
    (void)in_sizes; (void)n_in; (void)out_size; (void)ws_size;
    const float* inp   = (const float*)d_in[0];   // (64,32,32,8) fp32
    const float* W0f   = (const float*)d_in[1];   // (1536,520)  fp32
    const float* W1f   = (const float*)d_in[2];   // (1,1536,1024) fp32
    const float* Biasf = (const float*)d_in[3];   // (2,1536) fp32
    float* out = (float*)d_out;

    // ws layout (~13.2 MB): [W0p bf16 | W1p bf16 | flags 512 int | xb0 | xb1]
    unsigned short* W0p = (unsigned short*)d_ws;
    unsigned short* W1p = W0p + W0P_ELEMS;
    int* flags = (int*)(W1p + W1P_ELEMS);
    unsigned short* xb0 = (unsigned short*)(flags + 512);
    unsigned short* xb1 = xb0 + XB_ELEMS;

    convert_w<<<dim3(512), dim3(256), 0, stream>>>(W0f, W1f, W0p, W1p, flags);
    witran_coop<<<dim3(256), dim3(512), 0, stream>>>(inp, W0p, W1p, Biasf, out,
                                                     xb0, xb1, flags);
}

// Round 7
// 1932.928 us; speedup vs baseline: 5.3754x; 1.1440x over previous
//
#include <hip/hip_runtime.h>

typedef __bf16 bf16x8 __attribute__((ext_vector_type(8)));
typedef float  f32x4  __attribute__((ext_vector_type(4)));

#define Z0S 520   // z0 row (elems): [h_row 0:256 | h_col 256:512 | x 512:520]
#define Z1S 1032  // z1 row: [h_row | h_col | x_row 512:768 | x_col 768:1024] + 8 pad
#define W0P_ELEMS (2 * 8 * 17 * 6 * 512)   // packed W0: [gcg 0..15][ks0..16][G][lane][8]
#define W1P_ELEMS (2 * 8 * 32 * 6 * 512)   // packed W1: [gcg 0..15][ks0..31][G][lane][8]
#define XB_ELEMS (2 * 64 * 32 * 512)       // [slot][b][m][c] bf16, c = region*256+col

__device__ __forceinline__ unsigned short f2bf(float f) {
    unsigned int u = __builtin_bit_cast(unsigned int, f);
    u += 0x7fffu + ((u >> 16) & 1u);   // RNE
    return (unsigned short)(u >> 16);
}
__device__ __forceinline__ float sigm(float x) {
    x = fminf(30.f, fmaxf(-30.f, x));
    return __fdividef(1.0f, 1.0f + __expf(-x));
}
__device__ __forceinline__ float ftanh(float x) {
    x = fminf(15.f, fmaxf(-15.f, x));
    float e = __expf(2.0f * x);
    return 1.0f - __fdividef(2.0f, e + 1.0f);
}
__device__ __forceinline__ bf16x8 zero8() {
    bf16x8 v;
#pragma unroll
    for (int i = 0; i < 8; ++i) v[i] = (__bf16)0.0f;
    return v;
}
// L2-bypassing stores (write-through): output/exchange streams must NOT
// allocate in L2 (round-3/4: write streams were evicting the weight slice).
__device__ __forceinline__ void st_f32_wt(float* p, float v) {
    __hip_atomic_store(p, v, __ATOMIC_RELAXED, __HIP_MEMORY_SCOPE_AGENT);
}
__device__ __forceinline__ void st_u16_wt(unsigned short* p, unsigned short v) {
    __hip_atomic_store(p, v, __ATOMIC_RELAXED, __HIP_MEMORY_SCOPE_AGENT);
}

// fp32 -> bf16 weight conversion + MFMA-fragment packing + flag zeroing.
// Packed layout: Wp[gcg=jj>>4][ks][G][lane=quad*16+l16][8] -> each wave-level
// B-fragment load is one contiguous 1 KB block (fully coalesced).
__global__ void convert_w(const float* __restrict__ W0f, const float* __restrict__ W1f,
                          unsigned short* __restrict__ W0p, unsigned short* __restrict__ W1p,
                          int* __restrict__ flags) {
    const int gid = blockIdx.x * blockDim.x + threadIdx.x;
    const int stride = gridDim.x * blockDim.x;
    if (gid < 512) flags[gid] = 0;
    for (int i = gid; i < W0P_ELEMS; i += stride) {
        const int e = i & 7, lane = (i >> 3) & 63;
        const int r = i >> 9;
        const int G = r % 6;  const int r2 = r / 6;
        const int ks = r2 % 17; const int gcg = r2 / 17;    // 0..15
        const int jj = gcg * 16 + (lane & 15);
        const int k = ks * 32 + (lane >> 4) * 8 + e;
        float v = 0.f;
        if (k < 520) v = W0f[(size_t)(G * 256 + jj) * 520 + k];
        W0p[i] = f2bf(v);
    }
    for (int i = gid; i < W1P_ELEMS; i += stride) {
        const int e = i & 7, lane = (i >> 3) & 63;
        const int r = i >> 9;
        const int G = r % 6;  const int r2 = r / 6;
        const int ks = r2 & 31; const int gcg = r2 >> 5;    // 0..15
        const int jj = gcg * 16 + (lane & 15);
        const int k = ks * 32 + (lane >> 4) * 8 + e;
        W1p[i] = f2bf(W1f[(size_t)(G * 256 + jj) * 1024 + k]);
    }
}

// 256 blocks = 64 batches x 4 column-slices (64 cols each); 512 threads =
// 8 waves = 4 col-groups x 2 GATE-halves. Round-5 PMC confirmed
// L1-delivery-bound: the old mh-pair waves loaded identical B-fragments
// twice (2.35 MB/step issued, 1.18 MB distinct). The WITRAN update is
// gate-separable: h_row needs only {G0,G1,G4}, h_col only {G2,G3,G5},
// same formula. So wave gh=0 = row-wave (3 gates, both m-tiles, owns
// h_row), gh=1 = col-wave (3 gates, both m-tiles, owns h_col + roll).
// Every B-fragment is now loaded exactly once per CU -> L1 traffic halves;
// MFMA count unchanged; numerics identical. All gh-branches wave-uniform;
// barriers outside divergent regions. Exchange protocol unchanged.
// (Resubmission of round 6 -- container-level infra failure, no verdict.)
__global__ __launch_bounds__(512, 2) void witran_coop(
    const float* __restrict__ inp,             // (64,32,32,8) fp32
    const unsigned short* __restrict__ W0p,    // packed bf16
    const unsigned short* __restrict__ W1p,    // packed bf16
    const float* __restrict__ Bias,            // (2,1536)    fp32
    float* __restrict__ out,                   // fp32 outputs
    unsigned short* __restrict__ xb0,          // exchange: layer-0 images
    unsigned short* __restrict__ xb1,          // exchange: layer-1 state
    int* __restrict__ flags)                   // [256] f0 | [256] f1
{
    const int bid  = blockIdx.x;
    const int r8   = bid & 7;
    const int s    = r8 >> 1;                        // slice 0..3 (XCD pair)
    const int b    = (bid >> 3) * 2 + (r8 & 1);      // batch 0..63
    const int tid  = threadIdx.x;
    const int wave = tid >> 6;                       // 0..7
    const int cg   = wave >> 1;                      // col-group 0..3
    const int gh   = wave & 1;                       // 0 = row-wave, 1 = col-wave
    const int lane = tid & 63;
    const int quad = lane >> 4;
    const int l16  = lane & 15;
    const int jl   = cg * 16 + l16;                  // local col 0..63
    const int jj   = s * 64 + jl;                    // absolute col 0..255
    const int gcg  = jj >> 4;                        // global col-group 0..15
    // gate set: row {0,1,4} = {u_r,o_r,i_r}; col {2,3,5} = {u_c,o_c,i_c}
    const int Gs0 = 2 * gh, Gs1 = 2 * gh + 1, Gs2 = 4 + gh;

    int* f0 = flags;
    int* f1 = flags + 256;
    const int fown = b * 4 + s;

    __shared__ __align__(16) unsigned short z0[32 * Z0S];
    __shared__ __align__(16) unsigned short z1[32 * Z1S];
    __shared__ float rollbuf[32 * 64];

    for (int idx = tid; idx < 32 * Z0S; idx += 512) z0[idx] = 0;
    for (int idx = tid; idx < 32 * Z1S; idx += 512) z1[idx] = 0;
    __syncthreads();
    if (tid < 256) {                           // stage x for t=0
        const int m = tid >> 3, i = tid & 7;
        const int c = 0 - m;
        float v = 0.f;
        if (c >= 0 && c < 32) v = inp[((b * 32 + m) * 32 + c) * 8 + i];
        z0[m * Z0S + 512 + i] = f2bf(v);
    }

    float biasr[2][3];
#pragma unroll
    for (int L = 0; L < 2; ++L) {
        biasr[L][0] = Bias[L * 1536 + Gs0 * 256 + jj];
        biasr[L][1] = Bias[L * 1536 + Gs1 * 256 + jj];
        biasr[L][2] = Bias[L * 1536 + Gs2 * 256 + jj];
    }

    // own-state regs: h_row for row-waves, h_col for col-waves.
    // streg[L][mh][p] <-> row m = mh*16+quad*4+p, col jj
    float streg[2][2][4];
#pragma unroll
    for (int L = 0; L < 2; ++L)
#pragma unroll
        for (int mh = 0; mh < 2; ++mh)
#pragma unroll
            for (int p = 0; p < 4; ++p) streg[L][mh][p] = 0.f;

    // wave-level packed weight bases (3 gate groups each); frag = 1 KB block
    const unsigned short* w0g[3];
    const unsigned short* w1g[3];
    w0g[0] = W0p + (size_t)gcg * (17 * 6 * 512) + Gs0 * 512 + lane * 8;
    w0g[1] = W0p + (size_t)gcg * (17 * 6 * 512) + Gs1 * 512 + lane * 8;
    w0g[2] = W0p + (size_t)gcg * (17 * 6 * 512) + Gs2 * 512 + lane * 8;
    w1g[0] = W1p + (size_t)gcg * (32 * 6 * 512) + Gs0 * 512 + lane * 8;
    w1g[1] = W1p + (size_t)gcg * (32 * 6 * 512) + Gs1 * 512 + lane * 8;
    w1g[2] = W1p + (size_t)gcg * (32 * 6 * 512) + Gs2 * 512 + lane * 8;
    const unsigned short* aB0m[2] = { &z0[l16 * Z0S], &z0[(16 + l16) * Z0S] };
    const unsigned short* aB1m[2] = { &z1[l16 * Z1S], &z1[(16 + l16) * Z1S] };

    __syncthreads();

    const size_t OUT1 = 66060288u;           // hidden_row_all (64,2,32,256)
    const size_t OUT2 = OUT1 + 1048576u;     // hidden_col_all (64,2,32,256)

    // partner-staging decomposition: 512 threads = 32 rows x 2 regions x 8 chunks
    const int sr   = tid >> 4;               // row 0..31
    const int srem = tid & 15;
    const int sreg = srem >> 3;              // 0 = h_row, 1 = h_col
    const int sc8  = (srem & 7) * 8;         // chunk offset within 64-col slice
    const int sr1  = (sr + 1) & 31;

    for (int t = 0; t < 63; ++t) {
        float snew[2][4];
        // ============ phase A: GEMM0 (reads z0) + gating0 ============
        f32x4 acc[3][2];
        bf16x8 bA[3], bB[3];
#pragma unroll
        for (int i = 0; i < 3; ++i)
#pragma unroll
            for (int mh = 0; mh < 2; ++mh) acc[i][mh] = (f32x4){0.f, 0.f, 0.f, 0.f};
#pragma unroll
        for (int i = 0; i < 3; ++i) bA[i] = *(const bf16x8*)&w0g[i][0];

#pragma unroll 4
        for (int kp = 0; kp < 8; ++kp) {
            bf16x8 a00 = *(const bf16x8*)&aB0m[0][(2 * kp) * 32 + quad * 8];
            bf16x8 a01 = *(const bf16x8*)&aB0m[1][(2 * kp) * 32 + quad * 8];
            bf16x8 a10 = *(const bf16x8*)&aB0m[0][(2 * kp + 1) * 32 + quad * 8];
            bf16x8 a11 = *(const bf16x8*)&aB0m[1][(2 * kp + 1) * 32 + quad * 8];
#pragma unroll
            for (int i = 0; i < 3; ++i) bB[i] = *(const bf16x8*)&w0g[i][(2 * kp + 1) * 3072];
#pragma unroll
            for (int i = 0; i < 3; ++i) {
                acc[i][0] = __builtin_amdgcn_mfma_f32_16x16x32_bf16(a00, bA[i], acc[i][0], 0, 0, 0);
                acc[i][1] = __builtin_amdgcn_mfma_f32_16x16x32_bf16(a01, bA[i], acc[i][1], 0, 0, 0);
            }
#pragma unroll
            for (int i = 0; i < 3; ++i) bA[i] = *(const bf16x8*)&w0g[i][(2 * kp + 2) * 3072];
#pragma unroll
            for (int i = 0; i < 3; ++i) {
                acc[i][0] = __builtin_amdgcn_mfma_f32_16x16x32_bf16(a10, bB[i], acc[i][0], 0, 0, 0);
                acc[i][1] = __builtin_amdgcn_mfma_f32_16x16x32_bf16(a11, bB[i], acc[i][1], 0, 0, 0);
            }
        }
        {   // ks=16 partial (in bA): x cols 512..519 on quad 0; B zero-padded
            bf16x8 a0 = zero8(), a1 = zero8();
            if (quad == 0) {
                a0 = *(const bf16x8*)&aB0m[0][512];
                a1 = *(const bf16x8*)&aB0m[1][512];
            }
#pragma unroll
            for (int i = 0; i < 3; ++i) {
                acc[i][0] = __builtin_amdgcn_mfma_f32_16x16x32_bf16(a0, bA[i], acc[i][0], 0, 0, 0);
                acc[i][1] = __builtin_amdgcn_mfma_f32_16x16x32_bf16(a1, bA[i], acc[i][1], 0, 0, 0);
            }
        }

#pragma unroll
        for (int mh = 0; mh < 2; ++mh)
#pragma unroll
            for (int p = 0; p < 4; ++p) {
                const int m = mh * 16 + quad * 4 + p;
                float gu = acc[0][mh][p], go = acc[1][mh][p], gi = acc[2][mh][p];
                if ((t < 32) && (m <= t)) {
                    gu += biasr[0][0]; go += biasr[0][1]; gi += biasr[0][2];
                }
                const float u = sigm(gu), o = sigm(go), ii = ftanh(gi);
                snew[mh][p] = ftanh((1.f - u) * streg[0][mh][p] + u * ii) * o;
            }
        if (gh == 0) {   // row state updates immediately; col state via rollbuf roll
#pragma unroll
            for (int mh = 0; mh < 2; ++mh)
#pragma unroll
                for (int p = 0; p < 4; ++p) streg[0][mh][p] = snew[mh][p];
        }
        __syncthreads();   // B1: all z0 reads of step t done

        // ============ phase B: layer-0 epilogue + publish ============
#pragma unroll
        for (int mh = 0; mh < 2; ++mh)
#pragma unroll
            for (int p = 0; p < 4; ++p) {
                const int m  = mh * 16 + quad * 4 + p;
                const float f = snew[mh][p];
                const unsigned short hb = f2bf(f);
                const size_t xi = ((size_t)((t & 1) * 64 + b) * 32 + m) * 512;
                if (gh == 0) {   // h_row side
                    z0[m * Z0S + jj] = hb;
                    z1[m * Z1S + 512 + jj] = hb;             // layer-1 x_row
                    st_u16_wt(&xb0[xi + jj], hb);
                    if (t >= 31 && m == t - 31)
                        st_f32_wt(&out[OUT1 + ((size_t)(b * 2 + 0) * 32 + (t - 31)) * 256 + jj], f);
                } else {         // h_col side
                    z0[((m + 1) & 31) * Z0S + 256 + jj] = hb; // rolled h_col
                    z1[m * Z1S + 768 + jj] = hb;              // layer-1 x_col (unrolled)
                    rollbuf[m * 64 + jl] = f;
                    st_u16_wt(&xb0[xi + 256 + jj], hb);
                    if (t >= 31 && m == 31)
                        st_f32_wt(&out[OUT2 + ((size_t)(b * 2 + 0) * 32 + (t - 31)) * 256 + jj], f);
                }
            }
        if (tid < 256 && t + 1 < 63) {     // stage x for t+1
            const int m = tid >> 3, i = tid & 7;
            const int c = t + 1 - m;
            float v = 0.f;
            if (c >= 0 && c < 32) v = inp[((b * 32 + m) * 32 + c) * 8 + i];
            z0[m * Z0S + 512 + i] = f2bf(v);
        }
        __syncthreads();   // B2a: own writes done (s_barrier drains vmcnt)

        if (tid == 0)
            __hip_atomic_store(&f0[fown], t + 1, __ATOMIC_RELEASE, __HIP_MEMORY_SCOPE_AGENT);

        // roll readback, layer 0 (col-waves): new h_col[m] = computed[(m-1) mod 32]
        if (gh == 1) {
#pragma unroll
            for (int mh = 0; mh < 2; ++mh)
#pragma unroll
                for (int p = 0; p < 4; ++p) {
                    const int m = mh * 16 + quad * 4 + p;
                    streg[0][mh][p] = rollbuf[((m + 31) & 31) * 64 + jl];
                }
        }

        // wait for 3 partner slices: layer-0 step t, layer-1 step t-1.
        // RELAXED agent loads only -- per-access coherent, no L2 invalidate.
        if (tid == 0) {
#pragma unroll
            for (int j = 1; j < 4; ++j) {
                const int fp = b * 4 + ((s + j) & 3);
                int it = 0;
                while (__hip_atomic_load(&f0[fp], __ATOMIC_RELAXED, __HIP_MEMORY_SCOPE_AGENT) < t + 1) {
                    __builtin_amdgcn_s_sleep(4);
                    if (++it > 4000000) break;
                }
                it = 0;
                while (__hip_atomic_load(&f1[fp], __ATOMIC_RELAXED, __HIP_MEMORY_SCOPE_AGENT) < t) {
                    __builtin_amdgcn_s_sleep(4);
                    if (++it > 4000000) break;
                }
            }
        }
        __syncthreads();   // Bp: partner-ready fact visible to all waves

        // partner staging: one 16 B chunk per partner slice per buffer per thread
        {
            const unsigned int* x0u = (const unsigned int*)xb0;
            const unsigned int* x1u = (const unsigned int*)xb1;
#pragma unroll
            for (int j = 1; j < 4; ++j) {
                const int q   = (s + j) & 3;
                const int col = q * 64 + sc8;
                union { unsigned int u4[4]; bf16x8 v; } q0, q1;
                const size_t e0 = (((size_t)((t & 1) * 64 + b) * 32 + sr) * 512 + sreg * 256 + col) >> 1;
#pragma unroll
                for (int w = 0; w < 4; ++w)
                    q0.u4[w] = __hip_atomic_load(&x0u[e0 + w], __ATOMIC_RELAXED, __HIP_MEMORY_SCOPE_AGENT);
                // layer-0 image (step t): z1 x-region (no roll) + z0 state (hcol rolled)
                *(bf16x8*)&z1[sr * Z1S + 512 + sreg * 256 + col] = q0.v;
                *(bf16x8*)&z0[(sreg ? sr1 : sr) * Z0S + sreg * 256 + col] = q0.v;
                if (t > 0) {   // layer-1 state (step t-1): hcol rolled
                    const size_t e1 = (((size_t)(((t + 1) & 1) * 64 + b) * 32 + sr) * 512 + sreg * 256 + col) >> 1;
#pragma unroll
                    for (int w = 0; w < 4; ++w)
                        q1.u4[w] = __hip_atomic_load(&x1u[e1 + w], __ATOMIC_RELAXED, __HIP_MEMORY_SCOPE_AGENT);
                    *(bf16x8*)&z1[(sreg ? sr1 : sr) * Z1S + sreg * 256 + col] = q1.v;
                }
            }
        }
        __syncthreads();   // B2b: z1 fully staged

        // ============ phase C: GEMM1 (reads z1) + gating1 ============
#pragma unroll
        for (int i = 0; i < 3; ++i)
#pragma unroll
            for (int mh = 0; mh < 2; ++mh) acc[i][mh] = (f32x4){0.f, 0.f, 0.f, 0.f};
#pragma unroll
        for (int i = 0; i < 3; ++i) bA[i] = *(const bf16x8*)&w1g[i][0];

#pragma unroll 4
        for (int kp = 0; kp < 16; ++kp) {
            bf16x8 a00 = *(const bf16x8*)&aB1m[0][(2 * kp) * 32 + quad * 8];
            bf16x8 a01 = *(const bf16x8*)&aB1m[1][(2 * kp) * 32 + quad * 8];
            bf16x8 a10 = *(const bf16x8*)&aB1m[0][(2 * kp + 1) * 32 + quad * 8];
            bf16x8 a11 = *(const bf16x8*)&aB1m[1][(2 * kp + 1) * 32 + quad * 8];
#pragma unroll
            for (int i = 0; i < 3; ++i) bB[i] = *(const bf16x8*)&w1g[i][(2 * kp + 1) * 3072];
#pragma unroll
            for (int i = 0; i < 3; ++i) {
                acc[i][0] = __builtin_amdgcn_mfma_f32_16x16x32_bf16(a00, bA[i], acc[i][0], 0, 0, 0);
                acc[i][1] = __builtin_amdgcn_mfma_f32_16x16x32_bf16(a01, bA[i], acc[i][1], 0, 0, 0);
            }
            const int kn = (kp < 15) ? (2 * kp + 2) : 31;   // clamp: last prefetch redundant
#pragma unroll
            for (int i = 0; i < 3; ++i) bA[i] = *(const bf16x8*)&w1g[i][kn * 3072];
#pragma unroll
            for (int i = 0; i < 3; ++i) {
                acc[i][0] = __builtin_amdgcn_mfma_f32_16x16x32_bf16(a10, bB[i], acc[i][0], 0, 0, 0);
                acc[i][1] = __builtin_amdgcn_mfma_f32_16x16x32_bf16(a11, bB[i], acc[i][1], 0, 0, 0);
            }
        }

#pragma unroll
        for (int mh = 0; mh < 2; ++mh)
#pragma unroll
            for (int p = 0; p < 4; ++p) {
                const int m = mh * 16 + quad * 4 + p;
                float gu = acc[0][mh][p], go = acc[1][mh][p], gi = acc[2][mh][p];
                if ((t < 32) && (m <= t)) {
                    gu += biasr[1][0]; go += biasr[1][1]; gi += biasr[1][2];
                }
                const float u = sigm(gu), o = sigm(go), ii = ftanh(gi);
                snew[mh][p] = ftanh((1.f - u) * streg[1][mh][p] + u * ii) * o;
            }
        if (gh == 0) {
#pragma unroll
            for (int mh = 0; mh < 2; ++mh)
#pragma unroll
                for (int p = 0; p < 4; ++p) streg[1][mh][p] = snew[mh][p];
        }
        __syncthreads();   // B3: all z1 reads of step t done

        // ============ phase D: layer-1 epilogue + publish ============
#pragma unroll
        for (int mh = 0; mh < 2; ++mh)
#pragma unroll
            for (int p = 0; p < 4; ++p) {
                const int m  = mh * 16 + quad * 4 + p;
                const float f = snew[mh][p];
                const unsigned short hb = f2bf(f);
                const size_t xi = ((size_t)((t & 1) * 64 + b) * 32 + m) * 512;
                const size_t row = (size_t)(m * 64 + b);
                if (gh == 0) {   // h_row side
                    z1[m * Z1S + jj] = hb;
                    st_u16_wt(&xb1[xi + jj], hb);
                    st_f32_wt(&out[(row * 63 + t) * 512 + jj], f);          // output_all row half
                    if (t >= 31 && m == t - 31)
                        st_f32_wt(&out[OUT1 + ((size_t)(b * 2 + 1) * 32 + (t - 31)) * 256 + jj], f);
                } else {         // h_col side
                    z1[((m + 1) & 31) * Z1S + 256 + jj] = hb;
                    rollbuf[m * 64 + jl] = f;
                    st_u16_wt(&xb1[xi + 256 + jj], hb);
                    st_f32_wt(&out[(row * 63 + t) * 512 + 256 + jj], f);    // output_all col half
                    if (t >= 31 && m == 31)
                        st_f32_wt(&out[OUT2 + ((size_t)(b * 2 + 1) * 32 + (t - 31)) * 256 + jj], f);
                }
            }
        __syncthreads();   // B4: z1 state + rollbuf published (vmcnt drained)

        if (tid == 0)
            __hip_atomic_store(&f1[fown], t + 1, __ATOMIC_RELEASE, __HIP_MEMORY_SCOPE_AGENT);

        if (gh == 1) {   // roll readback, layer 1
#pragma unroll
            for (int mh = 0; mh < 2; ++mh)
#pragma unroll
                for (int p = 0; p < 4; ++p) {
                    const int m = mh * 16 + quad * 4 + p;
                    streg[1][mh][p] = rollbuf[((m + 31) & 31) * 64 + jl];
                }
        }
    }
}

extern "C" void kernel_launch(void* const* d_in, const int* in_sizes, int n_in,
                              void* d_out, int out_size, void* d_ws, size_t ws_size,
                              hipStream_t stream) {
    (void)in_sizes; (void)n_in; (void)out_size; (void)ws_size;
    const float* inp   = (const float*)d_in[0];   // (64,32,32,8) fp32
    const float* W0f   = (const float*)d_in[1];   // (1536,520)  fp32
    const float* W1f   = (const float*)d_in[2];   // (1,1536,1024) fp32
    const float* Biasf = (const float*)d_in[3];   // (2,1536) fp32
    float* out = (float*)d_out;

    // ws layout (~13.2 MB): [W0p bf16 | W1p bf16 | flags 512 int | xb0 | xb1]
    unsigned short* W0p = (unsigned short*)d_ws;
    unsigned short* W1p = W0p + W0P_ELEMS;
    int* flags = (int*)(W1p + W1P_ELEMS);
    unsigned short* xb0 = (unsigned short*)(flags + 512);
    unsigned short* xb1 = xb0 + XB_ELEMS;

    convert_w<<<dim3(512), dim3(256), 0, stream>>>(W0f, W1f, W0p, W1p, flags);
    witran_coop<<<dim3(256), dim3(512), 0, stream>>>(inp, W0p, W1p, Biasf, out,
                                                     xb0, xb1, flags);
}